// Round 1
// baseline (4095.946 us; speedup 1.0000x reference)
//
#include <hip/hip_runtime.h>
#include <hip/hip_bf16.h>
#include <math.h>

#define B_     64
#define NSM_   400
#define NLG_   196
#define SM_    512
#define LG_    1024
#define H_     16
#define DH_    64
#define INNER_ 1024

typedef __attribute__((ext_vector_type(8))) short bf16x8;
typedef __attribute__((ext_vector_type(4))) float f32x4;

__device__ __forceinline__ unsigned short f2b(float f) {
  unsigned u = __float_as_uint(f);
  u = u + 0x7FFFu + ((u >> 16) & 1u);   // RNE
  return (unsigned short)(u >> 16);
}
__device__ __forceinline__ float b2f(unsigned short b) {
  return __uint_as_float(((unsigned)b) << 16);
}

// ---------------------------------------------------------------- utilities
__global__ void copy_f32v4(const float* __restrict__ src, float* __restrict__ dst, int n4) {
  const float4* s = (const float4*)src;
  float4* d = (float4*)dst;
  for (int i = blockIdx.x * blockDim.x + threadIdx.x; i < n4; i += gridDim.x * blockDim.x)
    d[i] = s[i];
}

__global__ void copy_rows(const float* __restrict__ src, size_t sstride,
                          float* __restrict__ dst, size_t dstride, int rowlen) {
  int b = blockIdx.y;
  for (int i = blockIdx.x * 256 + threadIdx.x; i < rowlen; i += gridDim.x * 256)
    dst[(size_t)b * dstride + i] = src[(size_t)b * sstride + i];
}

// patches (rows 1..Nctx) of tokens -> contiguous bf16 [B*Nctx, dim]
__global__ void patches_to_bf16(const float* __restrict__ tok, unsigned short* __restrict__ dst,
                                int Nctx, int dim) {
  int b = blockIdx.y;
  const float* src = tok + ((size_t)b * (Nctx + 1) + 1) * dim;
  unsigned short* d = dst + (size_t)b * Nctx * dim;
  int n = Nctx * dim;
  for (int i = blockIdx.x * 256 + threadIdx.x; i < n; i += gridDim.x * 256)
    d[i] = f2b(src[i]);
}

// w: (L,K,N) f32 -> wt: (L,N,K) bf16
__global__ void transpose_to_bf16(const float* __restrict__ w, unsigned short* __restrict__ wt,
                                  int K, int N) {
  __shared__ unsigned short tile[64][65];
  const float* wp = w + (size_t)blockIdx.z * K * N;
  unsigned short* op = wt + (size_t)blockIdx.z * K * N;
  int kt = blockIdx.y * 64, nt = blockIdx.x * 64;
  int tx = threadIdx.x, ty = threadIdx.y;  // (64,4)
  for (int r = ty; r < 64; r += 4)
    tile[r][tx] = f2b(wp[(size_t)(kt + r) * N + nt + tx]);
  __syncthreads();
  for (int r = ty; r < 64; r += 4)
    op[(size_t)(nt + r) * K + kt + tx] = tile[tx][r];
}

// ------------------------------------------------------------ big KV GEMM
// C[M,2048] = A[M,K] * B[K,2048], with BT given as (2048,K), all bf16, fp32 acc.
__global__ __launch_bounds__(256) void gemm_kv(const unsigned short* __restrict__ A,
                                               const unsigned short* __restrict__ BT,
                                               unsigned short* __restrict__ C, int K) {
  __shared__ unsigned short As[128][40];  // +8 pad: rows 16B-aligned, conflict-free frag reads
  __shared__ unsigned short Bs[128][40];
  const int t = threadIdx.x;
  const int lane = t & 63;
  const int w = t >> 6;
  const int wr = w >> 1, wc = w & 1;
  const int tile_m = blockIdx.y * 128;
  const int tile_n = blockIdx.x * 128;
  const int r16 = lane & 15;
  const int kv8 = (lane >> 4) * 8;

  f32x4 acc[4][4];
#pragma unroll
  for (int mi = 0; mi < 4; mi++)
#pragma unroll
    for (int ni = 0; ni < 4; ni++) {
      acc[mi][ni][0] = 0.f; acc[mi][ni][1] = 0.f;
      acc[mi][ni][2] = 0.f; acc[mi][ni][3] = 0.f;
    }

  for (int k0 = 0; k0 < K; k0 += 32) {
    __syncthreads();
#pragma unroll
    for (int p = 0; p < 2; p++) {
      int e = t + p * 256;
      int row = e >> 2, kg = (e & 3) * 8;
      *(bf16x8*)&As[row][kg] = *(const bf16x8*)&A[(size_t)(tile_m + row) * K + k0 + kg];
      *(bf16x8*)&Bs[row][kg] = *(const bf16x8*)&BT[(size_t)(tile_n + row) * K + k0 + kg];
    }
    __syncthreads();
    bf16x8 af[4], bfr[4];
#pragma unroll
    for (int mi = 0; mi < 4; mi++)
      af[mi] = *(const bf16x8*)&As[wr * 64 + mi * 16 + r16][kv8];
#pragma unroll
    for (int ni = 0; ni < 4; ni++)
      bfr[ni] = *(const bf16x8*)&Bs[wc * 64 + ni * 16 + r16][kv8];
#pragma unroll
    for (int mi = 0; mi < 4; mi++)
#pragma unroll
      for (int ni = 0; ni < 4; ni++)
        acc[mi][ni] = __builtin_amdgcn_mfma_f32_16x16x32_bf16(af[mi], bfr[ni], acc[mi][ni], 0, 0, 0);
  }

  const int rbase = (lane >> 4) * 4;
#pragma unroll
  for (int mi = 0; mi < 4; mi++)
#pragma unroll
    for (int ni = 0; ni < 4; ni++)
#pragma unroll
      for (int rr = 0; rr < 4; rr++) {
        int row = tile_m + wr * 64 + mi * 16 + rbase + rr;
        int col = tile_n + wc * 64 + ni * 16 + r16;
        C[(size_t)row * 2048 + col] = f2b(acc[mi][ni][rr]);
      }
}

// ----------------------------------------------------- small fp32 GEMM, M=64
// C[64,N] = A[64,K] @ W[K,N] (+bias) (+residual into C)
__global__ __launch_bounds__(256) void smallgemm64(const float* __restrict__ A,
                                                   const float* __restrict__ W,
                                                   const float* __restrict__ bias,
                                                   float* __restrict__ C,
                                                   int K, int N, int addResidual) {
  __shared__ float As[64][33];
  __shared__ float Ws[32][65];
  const int t = threadIdx.x;
  const int tx = t & 15, ty = t >> 4;
  const int n0 = blockIdx.x * 64;
  float acc[4][4];
#pragma unroll
  for (int i = 0; i < 4; i++)
#pragma unroll
    for (int j = 0; j < 4; j++) acc[i][j] = 0.f;

  for (int k0 = 0; k0 < K; k0 += 32) {
    __syncthreads();
#pragma unroll
    for (int l = 0; l < 8; l++) {
      int e = t + 256 * l;
      int r = e >> 5, kk = e & 31;
      As[r][kk] = A[(size_t)r * K + k0 + kk];
    }
#pragma unroll
    for (int l = 0; l < 8; l++) {
      int e = t + 256 * l;
      int kk = e >> 6, n = e & 63;
      Ws[kk][n] = W[(size_t)(k0 + kk) * N + n0 + n];
    }
    __syncthreads();
#pragma unroll
    for (int kk = 0; kk < 32; kk++) {
      float a0 = As[ty * 4 + 0][kk], a1 = As[ty * 4 + 1][kk];
      float a2 = As[ty * 4 + 2][kk], a3 = As[ty * 4 + 3][kk];
      float b0 = Ws[kk][tx * 4 + 0], b1 = Ws[kk][tx * 4 + 1];
      float b2 = Ws[kk][tx * 4 + 2], b3 = Ws[kk][tx * 4 + 3];
      acc[0][0] += a0 * b0; acc[0][1] += a0 * b1; acc[0][2] += a0 * b2; acc[0][3] += a0 * b3;
      acc[1][0] += a1 * b0; acc[1][1] += a1 * b1; acc[1][2] += a1 * b2; acc[1][3] += a1 * b3;
      acc[2][0] += a2 * b0; acc[2][1] += a2 * b1; acc[2][2] += a2 * b2; acc[2][3] += a2 * b3;
      acc[3][0] += a3 * b0; acc[3][1] += a3 * b1; acc[3][2] += a3 * b2; acc[3][3] += a3 * b3;
    }
  }
#pragma unroll
  for (int i = 0; i < 4; i++) {
    int r = ty * 4 + i;
#pragma unroll
    for (int j = 0; j < 4; j++) {
      int c = n0 + tx * 4 + j;
      float v = acc[i][j];
      if (bias) v += bias[c];
      if (addResidual) v += C[(size_t)r * N + c];
      C[(size_t)r * N + c] = v;
    }
  }
}

// --------------------------------------------------------------- layernorm
__global__ __launch_bounds__(256) void ln_kernel(const float* __restrict__ x,
                                                 float* __restrict__ xn,
                                                 const float* __restrict__ ng,
                                                 const float* __restrict__ nb, int dim) {
  int b = blockIdx.x, t = threadIdx.x;
  __shared__ float rs[4], rq[4], bc[2];
  const float* xp = x + (size_t)b * dim;
  float s = 0.f, sq = 0.f;
  for (int c = t; c < dim; c += 256) {
    float v = xp[c];
    s += v; sq += v * v;
  }
#pragma unroll
  for (int off = 32; off >= 1; off >>= 1) {
    s += __shfl_down(s, off);
    sq += __shfl_down(sq, off);
  }
  int w = t >> 6;
  if ((t & 63) == 0) { rs[w] = s; rq[w] = sq; }
  __syncthreads();
  if (t == 0) {
    float ts = rs[0] + rs[1] + rs[2] + rs[3];
    float tq = rq[0] + rq[1] + rq[2] + rq[3];
    float mu = ts / dim;
    float var = tq / dim - mu * mu;
    bc[0] = mu; bc[1] = rsqrtf(var + 1e-5f);
  }
  __syncthreads();
  float mu = bc[0], r = bc[1];
  for (int c = t; c < dim; c += 256)
    xn[(size_t)b * dim + c] = (xp[c] - mu) * r * ng[c] + nb[c];
}

// --------------------------------------------------------------- attention
// q: (B,1024) f32; kvc: (B,2048) f32 (cls row kv); kvp: (B*Nctx,2048) bf16
__global__ __launch_bounds__(256) void attn_kernel(const float* __restrict__ qb,
                                                   const float* __restrict__ kvc,
                                                   const unsigned short* __restrict__ kvp,
                                                   float* __restrict__ ob, int Nctx) {
  const int bh = blockIdx.x;
  const int b = bh >> 4, h = bh & 15;
  const int Nk = Nctx + 1;
  const int t = threadIdx.x;
  __shared__ float qs[64];
  __shared__ float ebuf[512];
  __shared__ float rbuf[4];
  __shared__ float part[4][64];

  if (t < 64) qs[t] = qb[(size_t)b * INNER_ + h * DH_ + t];
  __syncthreads();

  float sv[2] = {-1e30f, -1e30f};
#pragma unroll
  for (int u = 0; u < 2; u++) {
    int j = t + u * 256;
    if (j < Nk) {
      float dot = 0.f;
      if (j == 0) {
        const float* kp = kvc + (size_t)b * 2048 + h * DH_;
#pragma unroll
        for (int d2 = 0; d2 < DH_; d2++) dot += qs[d2] * kp[d2];
      } else {
        const unsigned short* kp = kvp + ((size_t)b * Nctx + (j - 1)) * 2048 + h * DH_;
#pragma unroll
        for (int d2 = 0; d2 < DH_; d2++) dot += qs[d2] * b2f(kp[d2]);
      }
      sv[u] = dot * 0.125f;
    }
  }
  float lm = fmaxf(sv[0], sv[1]);
#pragma unroll
  for (int off = 32; off >= 1; off >>= 1) lm = fmaxf(lm, __shfl_down(lm, off));
  if ((t & 63) == 0) rbuf[t >> 6] = lm;
  __syncthreads();
  const float mx = fmaxf(fmaxf(rbuf[0], rbuf[1]), fmaxf(rbuf[2], rbuf[3]));
  __syncthreads();  // rbuf about to be reused

  float ls = 0.f;
#pragma unroll
  for (int u = 0; u < 2; u++) {
    int j = t + u * 256;
    if (j < Nk) {
      float e = expf(sv[u] - mx);
      ebuf[j] = e;
      ls += e;
    }
  }
#pragma unroll
  for (int off = 32; off >= 1; off >>= 1) ls += __shfl_down(ls, off);
  if ((t & 63) == 0) rbuf[t >> 6] = ls;
  __syncthreads();
  const float denom = rbuf[0] + rbuf[1] + rbuf[2] + rbuf[3];

  const int d = t & 63, g = t >> 6;
  float acc = 0.f;
  for (int j = g; j < Nk; j += 4) {
    float v;
    if (j == 0) v = kvc[(size_t)b * 2048 + 1024 + h * DH_ + d];
    else v = b2f(kvp[((size_t)b * Nctx + (j - 1)) * 2048 + 1024 + h * DH_ + d]);
    acc += ebuf[j] * v;
  }
  part[g][d] = acc;
  __syncthreads();
  if (t < 64)
    ob[(size_t)b * INNER_ + h * DH_ + t] =
        (part[0][t] + part[1][t] + part[2][t] + part[3][t]) / denom;
}

// --------------------------------------------------------------- host side
static void run_step(hipStream_t stream, int layer, float* cls, int din, int dout, int Nctx,
                     const unsigned short* Abf, const unsigned short* WT,
                     const float* pin_w, const float* pin_b, const float* ng, const float* nb,
                     const float* wq, const float* wkv, const float* wo, const float* wob,
                     const float* pout_w, const float* pout_b,
                     unsigned short* kvp, float* xbuf, float* xnbuf, float* qbuf, float* kvc,
                     float* obuf, float* t1) {
  int M = B_ * Nctx;
  gemm_kv<<<dim3(2048 / 128, M / 128), 256, 0, stream>>>(Abf, WT + (size_t)layer * 2048 * dout,
                                                         kvp, dout);
  smallgemm64<<<dout / 64, 256, 0, stream>>>(cls, pin_w + (size_t)layer * din * dout,
                                             pin_b + (size_t)layer * dout, xbuf, din, dout, 0);
  ln_kernel<<<B_, 256, 0, stream>>>(xbuf, xnbuf, ng + (size_t)layer * dout,
                                    nb + (size_t)layer * dout, dout);
  smallgemm64<<<INNER_ / 64, 256, 0, stream>>>(xnbuf, wq + (size_t)layer * dout * INNER_, nullptr,
                                               qbuf, dout, INNER_, 0);
  smallgemm64<<<2048 / 64, 256, 0, stream>>>(xnbuf, wkv + (size_t)layer * dout * 2048, nullptr,
                                             kvc, dout, 2048, 0);
  attn_kernel<<<B_ * H_, 256, 0, stream>>>(qbuf, kvc, kvp, obuf, Nctx);
  smallgemm64<<<dout / 64, 256, 0, stream>>>(obuf, wo + (size_t)layer * INNER_ * dout,
                                             wob + (size_t)layer * dout, t1, INNER_, dout, 0);
  smallgemm64<<<din / 64, 256, 0, stream>>>(t1, pout_w + (size_t)layer * dout * din,
                                            pout_b + (size_t)layer * din, cls, dout, din, 1);
}

extern "C" void kernel_launch(void* const* d_in, const int* in_sizes, int n_in,
                              void* d_out, int out_size, void* d_ws, size_t ws_size,
                              hipStream_t stream) {
  const float* sm_tokens = (const float*)d_in[0];
  const float* lg_tokens = (const float*)d_in[1];
  const float* a_pin_w  = (const float*)d_in[2];
  const float* a_pin_b  = (const float*)d_in[3];
  const float* a_ng     = (const float*)d_in[4];
  const float* a_nb     = (const float*)d_in[5];
  const float* a_wq     = (const float*)d_in[6];
  const float* a_wkv    = (const float*)d_in[7];
  const float* a_wo     = (const float*)d_in[8];
  const float* a_wob    = (const float*)d_in[9];
  const float* a_pout_w = (const float*)d_in[10];
  const float* a_pout_b = (const float*)d_in[11];
  const float* b_pin_w  = (const float*)d_in[12];
  const float* b_pin_b  = (const float*)d_in[13];
  const float* b_ng     = (const float*)d_in[14];
  const float* b_nb     = (const float*)d_in[15];
  const float* b_wq     = (const float*)d_in[16];
  const float* b_wkv    = (const float*)d_in[17];
  const float* b_wo     = (const float*)d_in[18];
  const float* b_wob    = (const float*)d_in[19];
  const float* b_pout_w = (const float*)d_in[20];
  const float* b_pout_b = (const float*)d_in[21];

  float* out = (float*)d_out;
  char* ws = (char*)d_ws;
  size_t off = 0;
  auto alloc = [&](size_t bytes) -> void* {
    void* p = ws + off;
    off += (bytes + 255) & ~(size_t)255;
    return p;
  };
  unsigned short* kvp    = (unsigned short*)alloc((size_t)B_ * NSM_ * 2048 * 2);   // 104.9 MB
  unsigned short* Abf_lg = (unsigned short*)alloc((size_t)B_ * NLG_ * LG_ * 2);    // 25.7 MB
  unsigned short* Abf_sm = (unsigned short*)alloc((size_t)B_ * NSM_ * SM_ * 2);    // 26.2 MB
  unsigned short* WTa    = (unsigned short*)alloc((size_t)4 * 2048 * LG_ * 2);     // 16.8 MB
  unsigned short* WTb    = (unsigned short*)alloc((size_t)4 * 2048 * SM_ * 2);     // 8.4 MB
  float* sm_cls = (float*)alloc((size_t)B_ * SM_ * 4);
  float* lg_cls = (float*)alloc((size_t)B_ * LG_ * 4);
  float* xbuf   = (float*)alloc((size_t)B_ * 1024 * 4);
  float* xnbuf  = (float*)alloc((size_t)B_ * 1024 * 4);
  float* qbuf   = (float*)alloc((size_t)B_ * 1024 * 4);
  float* kvc    = (float*)alloc((size_t)B_ * 2048 * 4);
  float* obuf   = (float*)alloc((size_t)B_ * 1024 * 4);
  float* t1     = (float*)alloc((size_t)B_ * 1024 * 4);
  (void)ws_size; (void)in_sizes; (void)n_in; (void)out_size;

  const size_t sm_elems = (size_t)B_ * (NSM_ + 1) * SM_;   // 13,140,992
  const size_t lg_elems = (size_t)B_ * (NLG_ + 1) * LG_;   // 12,910,592

  // output patches (cls rows overwritten at the end)
  copy_f32v4<<<2048, 256, 0, stream>>>(sm_tokens, out, (int)(sm_elems / 4));
  copy_f32v4<<<2048, 256, 0, stream>>>(lg_tokens, out + sm_elems, (int)(lg_elems / 4));
  // cls gather
  copy_rows<<<dim3(2, B_), 256, 0, stream>>>(sm_tokens, (size_t)(NSM_ + 1) * SM_, sm_cls, SM_, SM_);
  copy_rows<<<dim3(2, B_), 256, 0, stream>>>(lg_tokens, (size_t)(NLG_ + 1) * LG_, lg_cls, LG_, LG_);
  // patches -> bf16 (contiguous, cls dropped)
  patches_to_bf16<<<dim3(128, B_), 256, 0, stream>>>(lg_tokens, Abf_lg, NLG_, LG_);
  patches_to_bf16<<<dim3(128, B_), 256, 0, stream>>>(sm_tokens, Abf_sm, NSM_, SM_);
  // wkv -> transposed bf16 (N,K) per layer
  transpose_to_bf16<<<dim3(2048 / 64, LG_ / 64, 4), dim3(64, 4), 0, stream>>>(a_wkv, WTa, LG_, 2048);
  transpose_to_bf16<<<dim3(2048 / 64, SM_ / 64, 4), dim3(64, 4), 0, stream>>>(b_wkv, WTb, SM_, 2048);

  for (int i = 0; i < 4; i++) {
    run_step(stream, i, sm_cls, SM_, LG_, NLG_, Abf_lg, WTa,
             a_pin_w, a_pin_b, a_ng, a_nb, a_wq, a_wkv, a_wo, a_wob, a_pout_w, a_pout_b,
             kvp, xbuf, xnbuf, qbuf, kvc, obuf, t1);
    run_step(stream, i, lg_cls, LG_, SM_, NSM_, Abf_sm, WTb,
             b_pin_w, b_pin_b, b_ng, b_nb, b_wq, b_wkv, b_wo, b_wob, b_pout_w, b_pout_b,
             kvp, xbuf, xnbuf, qbuf, kvc, obuf, t1);
  }

  // final cls rows
  copy_rows<<<dim3(2, B_), 256, 0, stream>>>(sm_cls, SM_, out, (size_t)(NSM_ + 1) * SM_, SM_);
  copy_rows<<<dim3(2, B_), 256, 0, stream>>>(lg_cls, LG_, out + sm_elems, (size_t)(NLG_ + 1) * LG_, LG_);
}

// Round 2
// 2309.862 us; speedup vs baseline: 1.7732x; 1.7732x over previous
//
#include <hip/hip_runtime.h>
#include <hip/hip_bf16.h>
#include <math.h>

#define B_     64
#define NSM_   400
#define NLG_   196
#define SM_    512
#define LG_    1024
#define H_     16
#define DH_    64
#define INNER_ 1024
#define SMAX_  416   // row stride for S and p (max padded Nctx)

typedef __attribute__((ext_vector_type(8))) short bf16x8;
typedef __attribute__((ext_vector_type(4))) float f32x4;

__device__ __forceinline__ unsigned short f2b(float f) {
  unsigned u = __float_as_uint(f);
  u = u + 0x7FFFu + ((u >> 16) & 1u);   // RNE
  return (unsigned short)(u >> 16);
}
__device__ __forceinline__ float b2f(unsigned short b) {
  return __uint_as_float(((unsigned)b) << 16);
}

// ---------------------------------------------------------------- utilities
__global__ void copy_f32v4(const float* __restrict__ src, float* __restrict__ dst, int n4) {
  const float4* s = (const float4*)src;
  float4* d = (float4*)dst;
  for (int i = blockIdx.x * blockDim.x + threadIdx.x; i < n4; i += gridDim.x * blockDim.x)
    d[i] = s[i];
}

__global__ void copy_rows(const float* __restrict__ src, size_t sstride,
                          float* __restrict__ dst, size_t dstride, int rowlen) {
  int b = blockIdx.y;
  for (int i = blockIdx.x * 256 + threadIdx.x; i < rowlen; i += gridDim.x * 256)
    dst[(size_t)b * dstride + i] = src[(size_t)b * sstride + i];
}

// patches (rows 1..Nctx) of tokens -> contiguous bf16 [B*Nctx, dim]
__global__ void patches_to_bf16(const float* __restrict__ tok, unsigned short* __restrict__ dst,
                                int Nctx, int dim) {
  int b = blockIdx.y;
  const float* src = tok + ((size_t)b * (Nctx + 1) + 1) * dim;
  unsigned short* d = dst + (size_t)b * Nctx * dim;
  int n = Nctx * dim;
  for (int i = blockIdx.x * 256 + threadIdx.x; i < n; i += gridDim.x * 256)
    d[i] = f2b(src[i]);
}

// w: (L,K,N) f32 -> wt: (L,N,K) bf16
__global__ void transpose_to_bf16(const float* __restrict__ w, unsigned short* __restrict__ wt,
                                  int K, int N) {
  __shared__ unsigned short tile[64][65];
  const float* wp = w + (size_t)blockIdx.z * K * N;
  unsigned short* op = wt + (size_t)blockIdx.z * K * N;
  int kt = blockIdx.y * 64, nt = blockIdx.x * 64;
  int tx = threadIdx.x, ty = threadIdx.y;  // (64,4)
  for (int r = ty; r < 64; r += 4)
    tile[r][tx] = f2b(wp[(size_t)(kt + r) * N + nt + tx]);
  __syncthreads();
  for (int r = ty; r < 64; r += 4)
    op[(size_t)(nt + r) * K + kt + tx] = tile[tx][r];
}

// xbf [B*Nctx][dout] bf16 -> xT [B][dout][xstride] bf16, zero pad j>=Nctx
__global__ void transpose_x(const unsigned short* __restrict__ xbf,
                            unsigned short* __restrict__ xT,
                            int Nctx, int dout, int xstride) {
  __shared__ unsigned short tile[64][65];
  const int b = blockIdx.z;
  const int jt = blockIdx.y * 64, ct = blockIdx.x * 64;
  int tx = threadIdx.x, ty = threadIdx.y;  // (64,4)
  for (int r = ty; r < 64; r += 4) {
    int j = jt + r;
    tile[r][tx] = (j < Nctx) ? xbf[((size_t)b * Nctx + j) * dout + ct + tx]
                             : (unsigned short)0;
  }
  __syncthreads();
  for (int r = ty; r < 64; r += 4) {
    int col = jt + tx;
    if (col < xstride)
      xT[((size_t)b * dout + ct + r) * xstride + col] = tile[tx][r];
  }
}

// ------------------------------------------------- MFMA cls GEMM  (M = 64)
// C[64,N] f32 (stride N) = A[64,K] f32 (stride K) @ WT[N,K] bf16 (+bias)(+res)
__global__ __launch_bounds__(256) void clsgemm(const float* __restrict__ A,
                                               const unsigned short* __restrict__ WT,
                                               const float* __restrict__ bias,
                                               float* __restrict__ C,
                                               int K, int N, int addRes) {
  const int t = threadIdx.x, lane = t & 63, w = t >> 6;
  const int n0 = blockIdx.x * 64;
  const int r16 = lane & 15, kv8 = (lane >> 4) * 8;
  f32x4 acc[4];
#pragma unroll
  for (int nt = 0; nt < 4; nt++) { acc[nt][0]=0.f; acc[nt][1]=0.f; acc[nt][2]=0.f; acc[nt][3]=0.f; }
  const float* ap = A + (size_t)(w * 16 + r16) * K + kv8;
#pragma unroll 2
  for (int k0 = 0; k0 < K; k0 += 32) {
    bf16x8 af;
#pragma unroll
    for (int i = 0; i < 8; i++) af[i] = (short)f2b(ap[k0 + i]);
#pragma unroll
    for (int nt = 0; nt < 4; nt++) {
      bf16x8 bfr = *(const bf16x8*)&WT[(size_t)(n0 + nt * 16 + r16) * K + k0 + kv8];
      acc[nt] = __builtin_amdgcn_mfma_f32_16x16x32_bf16(af, bfr, acc[nt], 0, 0, 0);
    }
  }
  const int rbase = (lane >> 4) * 4;
#pragma unroll
  for (int nt = 0; nt < 4; nt++)
#pragma unroll
    for (int rr = 0; rr < 4; rr++) {
      int r = w * 16 + rbase + rr;
      int c = n0 + nt * 16 + r16;
      float v = acc[nt][rr];
      if (bias) v += bias[c];
      if (addRes) v += C[(size_t)r * N + c];
      C[(size_t)r * N + c] = v;
    }
}

// --------------------------------------------------------------- layernorm
__global__ __launch_bounds__(256) void ln_kernel(const float* __restrict__ x,
                                                 float* __restrict__ xn,
                                                 const float* __restrict__ ng,
                                                 const float* __restrict__ nb, int dim) {
  int b = blockIdx.x, t = threadIdx.x;
  __shared__ float rs[4], rq[4], bc[2];
  const float* xp = x + (size_t)b * dim;
  float s = 0.f, sq = 0.f;
  for (int c = t; c < dim; c += 256) {
    float v = xp[c];
    s += v; sq += v * v;
  }
#pragma unroll
  for (int off = 32; off >= 1; off >>= 1) {
    s += __shfl_down(s, off);
    sq += __shfl_down(sq, off);
  }
  int w = t >> 6;
  if ((t & 63) == 0) { rs[w] = s; rq[w] = sq; }
  __syncthreads();
  if (t == 0) {
    float ts = rs[0] + rs[1] + rs[2] + rs[3];
    float tq = rq[0] + rq[1] + rq[2] + rq[3];
    float mu = ts / dim;
    float var = tq / dim - mu * mu;
    bc[0] = mu; bc[1] = rsqrtf(var + 1e-5f);
  }
  __syncthreads();
  float mu = bc[0], r = bc[1];
  for (int c = t; c < dim; c += 256)
    xn[(size_t)b * dim + c] = (xp[c] - mu) * r * ng[c] + nb[c];
}

// -------------------------------------------------------------- q~ (VALU)
// qt[b][h][c] = f2b( sum_d q[b][h*64+d] * wkv[c][h*64+d] )   (f32 inputs)
__global__ __launch_bounds__(256) void qtilde_valu(const float* __restrict__ qbuf,
                                                   const float* __restrict__ wkv,
                                                   unsigned short* __restrict__ qt, int dout) {
  const int ct = blockIdx.x, h = blockIdx.y;
  __shared__ float qs[64][64];
  __shared__ float wsm[64][65];
  int t = threadIdx.x;
  for (int i = t; i < 64 * 64; i += 256) {
    int b = i >> 6, d = i & 63;
    qs[b][d] = qbuf[(size_t)b * INNER_ + h * 64 + d];
  }
  for (int i = t; i < 64 * 64; i += 256) {
    int c = i >> 6, d = i & 63;
    wsm[c][d] = wkv[(size_t)(ct * 64 + c) * 2048 + h * 64 + d];
  }
  __syncthreads();
  int b = t & 63, w = t >> 6;
  for (int c = w; c < 64; c += 4) {
    float s = 0.f;
#pragma unroll
    for (int d = 0; d < 64; d++) s += qs[b][d] * wsm[c][d];
    qt[((size_t)b * 16 + h) * dout + ct * 64 + c] = f2b(s);
  }
}

// ------------------------------------------------------- S = q~ . x^T (raw)
// S[b][h][j] = sum_c qt[b][h][c] * xbf[b*Nctx+j][c]
__global__ __launch_bounds__(256) void sgemm_s(const unsigned short* __restrict__ qt,
                                               const unsigned short* __restrict__ xbf,
                                               float* __restrict__ S,
                                               int dout, int Nctx, int Npad) {
  const int b = blockIdx.y;
  const int t = threadIdx.x, lane = t & 63, w = t >> 6;
  const int jt = blockIdx.x * 4 + w;
  if (jt >= Npad / 16) return;
  const int r16 = lane & 15, kv8 = (lane >> 4) * 8;
  const unsigned short* ap = qt + ((size_t)b * 16 + r16) * dout + kv8;
  const unsigned short* bp = xbf + ((size_t)b * Nctx + jt * 16 + r16) * dout + kv8;
  f32x4 acc; acc[0]=0.f; acc[1]=0.f; acc[2]=0.f; acc[3]=0.f;
#pragma unroll 4
  for (int k0 = 0; k0 < dout; k0 += 32) {
    bf16x8 af = *(const bf16x8*)&ap[k0];
    bf16x8 bfr = *(const bf16x8*)&bp[k0];
    acc = __builtin_amdgcn_mfma_f32_16x16x32_bf16(af, bfr, acc, 0, 0, 0);
  }
  const int rbase = (lane >> 4) * 4;
#pragma unroll
  for (int rr = 0; rr < 4; rr++)
    S[((size_t)b * 16 + rbase + rr) * SMAX_ + jt * 16 + r16] = acc[rr];
}

// ------------------------------------------------------------- softmax -> p
__global__ __launch_bounds__(256) void softmax_p(const float* __restrict__ S,
                                                 const float* __restrict__ qbuf,
                                                 const float* __restrict__ kvc,
                                                 unsigned short* __restrict__ p,
                                                 float* __restrict__ pcls,
                                                 int Nctx, int Npad) {
  const int h = blockIdx.x, b = blockIdx.y;
  const int t = threadIdx.x;
  __shared__ float red[4], bc;
  float sc = 0.f;
  if (t < 64) sc = qbuf[(size_t)b * INNER_ + h * 64 + t] * kvc[(size_t)b * 2048 + h * 64 + t];
#pragma unroll
  for (int o = 32; o >= 1; o >>= 1) sc += __shfl_down(sc, o);
  if (t == 0) bc = sc * 0.125f;
  __syncthreads();
  const float scls = bc;
  const float* Sp = S + ((size_t)b * 16 + h) * SMAX_;

  float sraw[2] = {-1e30f, -1e30f};
#pragma unroll
  for (int u2 = 0; u2 < 2; u2++) {
    int j = t + u2 * 256;
    if (j < Nctx) sraw[u2] = Sp[j] * 0.125f;
  }
  float mx = fmaxf(fmaxf(sraw[0], sraw[1]), scls);
#pragma unroll
  for (int o = 32; o >= 1; o >>= 1) mx = fmaxf(mx, __shfl_down(mx, o));
  if ((t & 63) == 0) red[t >> 6] = mx;
  __syncthreads();
  mx = fmaxf(fmaxf(red[0], red[1]), fmaxf(red[2], red[3]));
  __syncthreads();

  float e0 = (t < Nctx) ? expf(sraw[0] - mx) : 0.f;
  float e1 = (t + 256 < Nctx) ? expf(sraw[1] - mx) : 0.f;
  float ecls = expf(scls - mx);
  float ls = e0 + e1;
#pragma unroll
  for (int o = 32; o >= 1; o >>= 1) ls += __shfl_down(ls, o);
  if ((t & 63) == 0) red[t >> 6] = ls;
  __syncthreads();
  const float denom = red[0] + red[1] + red[2] + red[3] + ecls;
  const float inv = 1.f / denom;

  unsigned short* pp = p + ((size_t)b * 16 + h) * SMAX_;
  if (t < Nctx) pp[t] = f2b(e0 * inv);
  if (t + 256 < Nctx) pp[t + 256] = f2b(e1 * inv);
  for (int j = Nctx + t; j < Npad; j += 256) pp[j] = 0;
  if (t == 0) pcls[b * 16 + h] = ecls * inv;
}

// ------------------------------------------------------------ u = p . x
// u[b][h][c] = sum_j p[b][h][j] * xT[b][c][j]   (bf16 out)
__global__ __launch_bounds__(256) void ugemm(const unsigned short* __restrict__ p,
                                             const unsigned short* __restrict__ xT,
                                             unsigned short* __restrict__ u,
                                             int dout, int Kpad, int xstride) {
  const int b = blockIdx.y;
  const int t = threadIdx.x, lane = t & 63, w = t >> 6;
  const int c0 = blockIdx.x * 64 + w * 16;
  const int r16 = lane & 15, kv8 = (lane >> 4) * 8;
  const unsigned short* ap = p + ((size_t)b * 16 + r16) * SMAX_ + kv8;
  const unsigned short* bp = xT + ((size_t)b * dout + c0 + r16) * xstride + kv8;
  f32x4 acc; acc[0]=0.f; acc[1]=0.f; acc[2]=0.f; acc[3]=0.f;
#pragma unroll 2
  for (int k0 = 0; k0 < Kpad; k0 += 32) {
    bf16x8 af = *(const bf16x8*)&ap[k0];
    bf16x8 bfr = *(const bf16x8*)&bp[k0];
    acc = __builtin_amdgcn_mfma_f32_16x16x32_bf16(af, bfr, acc, 0, 0, 0);
  }
  const int rbase = (lane >> 4) * 4;
#pragma unroll
  for (int rr = 0; rr < 4; rr++)
    u[((size_t)b * 16 + rbase + rr) * dout + c0 + r16] = f2b(acc[rr]);
}

// ------------------------------------------------------------ o = u . Wv
// obuf[b][h*64+d] = sum_c u[b][h][c]*WT[1024+h*64+d][c] + pcls[b][h]*kvc[b][1024+h*64+d]
__global__ __launch_bounds__(256) void ogemm(const unsigned short* __restrict__ u,
                                             const unsigned short* __restrict__ WT,
                                             const float* __restrict__ kvc,
                                             const float* __restrict__ pcls,
                                             float* __restrict__ obuf, int dout) {
  const int h = blockIdx.x;
  const int t = threadIdx.x, lane = t & 63, w = t >> 6;
  const int r16 = lane & 15, kv8 = (lane >> 4) * 8;
  const unsigned short* ap = u + ((size_t)(w * 16 + r16) * 16 + h) * dout + kv8;
  f32x4 acc[4];
#pragma unroll
  for (int nt = 0; nt < 4; nt++) { acc[nt][0]=0.f; acc[nt][1]=0.f; acc[nt][2]=0.f; acc[nt][3]=0.f; }
#pragma unroll 2
  for (int k0 = 0; k0 < dout; k0 += 32) {
    bf16x8 af = *(const bf16x8*)&ap[k0];
#pragma unroll
    for (int nt = 0; nt < 4; nt++) {
      bf16x8 bfr = *(const bf16x8*)&WT[(size_t)(1024 + h * 64 + nt * 16 + r16) * dout + k0 + kv8];
      acc[nt] = __builtin_amdgcn_mfma_f32_16x16x32_bf16(af, bfr, acc[nt], 0, 0, 0);
    }
  }
  const int rbase = (lane >> 4) * 4;
#pragma unroll
  for (int nt = 0; nt < 4; nt++)
#pragma unroll
    for (int rr = 0; rr < 4; rr++) {
      int b = w * 16 + rbase + rr;
      int d = h * 64 + nt * 16 + r16;
      obuf[(size_t)b * INNER_ + d] = acc[nt][rr] + pcls[b * 16 + h] * kvc[(size_t)b * 2048 + 1024 + d];
    }
}

// --------------------------------------------------------------- host side
struct BranchPtrs {
  const float *pin_w, *pin_b, *ng, *nb, *wq, *wkv, *wo, *wob, *pout_w, *pout_b;
  const unsigned short *WTpin, *WTwq, *WTkv, *WTwo, *WTpout;
  const unsigned short *Abf, *xT;
  int din, dout, Nctx, Npad, xstride;
};

static void run_step(hipStream_t stream, int l, float* cls, const BranchPtrs& P,
                     float* xbuf, float* xnbuf, float* qbuf, float* kvc, float* obuf, float* t1,
                     unsigned short* qt, float* S, unsigned short* p, float* pcls,
                     unsigned short* u) {
  const int din = P.din, dout = P.dout;
  clsgemm<<<dout / 64, 256, 0, stream>>>(cls, P.WTpin + (size_t)l * din * dout,
                                         P.pin_b + (size_t)l * dout, xbuf, din, dout, 0);
  ln_kernel<<<B_, 256, 0, stream>>>(xbuf, xnbuf, P.ng + (size_t)l * dout,
                                    P.nb + (size_t)l * dout, dout);
  clsgemm<<<INNER_ / 64, 256, 0, stream>>>(xnbuf, P.WTwq + (size_t)l * dout * INNER_, nullptr,
                                           qbuf, dout, INNER_, 0);
  clsgemm<<<2048 / 64, 256, 0, stream>>>(xnbuf, P.WTkv + (size_t)l * dout * 2048, nullptr,
                                         kvc, dout, 2048, 0);
  qtilde_valu<<<dim3(dout / 64, H_), 256, 0, stream>>>(qbuf, P.wkv + (size_t)l * dout * 2048,
                                                       qt, dout);
  sgemm_s<<<dim3((P.Npad / 16 + 3) / 4, B_), 256, 0, stream>>>(qt, P.Abf, S, dout, P.Nctx, P.Npad);
  softmax_p<<<dim3(H_, B_), 256, 0, stream>>>(S, qbuf, kvc, p, pcls, P.Nctx, P.Npad);
  ugemm<<<dim3(dout / 64, B_), 256, 0, stream>>>(p, P.xT, u, dout, P.Npad, P.xstride);
  ogemm<<<H_, 256, 0, stream>>>(u, P.WTkv + (size_t)l * dout * 2048, kvc, pcls, obuf, dout);
  clsgemm<<<dout / 64, 256, 0, stream>>>(obuf, P.WTwo + (size_t)l * INNER_ * dout,
                                         P.wob + (size_t)l * dout, t1, INNER_, dout, 0);
  clsgemm<<<din / 64, 256, 0, stream>>>(t1, P.WTpout + (size_t)l * dout * din,
                                        P.pout_b + (size_t)l * din, cls, dout, din, 1);
}

extern "C" void kernel_launch(void* const* d_in, const int* in_sizes, int n_in,
                              void* d_out, int out_size, void* d_ws, size_t ws_size,
                              hipStream_t stream) {
  const float* sm_tokens = (const float*)d_in[0];
  const float* lg_tokens = (const float*)d_in[1];
  BranchPtrs A, Bp;
  A.pin_w  = (const float*)d_in[2];  A.pin_b  = (const float*)d_in[3];
  A.ng     = (const float*)d_in[4];  A.nb     = (const float*)d_in[5];
  A.wq     = (const float*)d_in[6];  A.wkv    = (const float*)d_in[7];
  A.wo     = (const float*)d_in[8];  A.wob    = (const float*)d_in[9];
  A.pout_w = (const float*)d_in[10]; A.pout_b = (const float*)d_in[11];
  Bp.pin_w  = (const float*)d_in[12]; Bp.pin_b  = (const float*)d_in[13];
  Bp.ng     = (const float*)d_in[14]; Bp.nb     = (const float*)d_in[15];
  Bp.wq     = (const float*)d_in[16]; Bp.wkv    = (const float*)d_in[17];
  Bp.wo     = (const float*)d_in[18]; Bp.wob    = (const float*)d_in[19];
  Bp.pout_w = (const float*)d_in[20]; Bp.pout_b = (const float*)d_in[21];
  A.din = SM_;  A.dout = LG_;  A.Nctx = NLG_; A.Npad = 224; A.xstride = 224;
  Bp.din = LG_; Bp.dout = SM_; Bp.Nctx = NSM_; Bp.Npad = 416; Bp.xstride = 416;

  float* out = (float*)d_out;
  char* ws = (char*)d_ws;
  size_t off = 0;
  auto alloc = [&](size_t bytes) -> void* {
    void* pt = ws + off;
    off += (bytes + 255) & ~(size_t)255;
    return pt;
  };
  unsigned short* Abf_lg = (unsigned short*)alloc((size_t)B_ * NLG_ * LG_ * 2);
  unsigned short* Abf_sm = (unsigned short*)alloc((size_t)B_ * NSM_ * SM_ * 2);
  unsigned short* xT_lg  = (unsigned short*)alloc((size_t)B_ * LG_ * 224 * 2);
  unsigned short* xT_sm  = (unsigned short*)alloc((size_t)B_ * SM_ * 416 * 2);
  unsigned short* WTkv_a = (unsigned short*)alloc((size_t)4 * 2048 * LG_ * 2);
  unsigned short* WTkv_b = (unsigned short*)alloc((size_t)4 * 2048 * SM_ * 2);
  unsigned short* WTpin_a = (unsigned short*)alloc((size_t)4 * SM_ * LG_ * 2);
  unsigned short* WTpin_b = (unsigned short*)alloc((size_t)4 * LG_ * SM_ * 2);
  unsigned short* WTwq_a  = (unsigned short*)alloc((size_t)4 * LG_ * INNER_ * 2);
  unsigned short* WTwq_b  = (unsigned short*)alloc((size_t)4 * SM_ * INNER_ * 2);
  unsigned short* WTwo_a  = (unsigned short*)alloc((size_t)4 * INNER_ * LG_ * 2);
  unsigned short* WTwo_b  = (unsigned short*)alloc((size_t)4 * INNER_ * SM_ * 2);
  unsigned short* WTpout_a = (unsigned short*)alloc((size_t)4 * LG_ * SM_ * 2);
  unsigned short* WTpout_b = (unsigned short*)alloc((size_t)4 * SM_ * LG_ * 2);
  unsigned short* qt  = (unsigned short*)alloc((size_t)B_ * 16 * 1024 * 2);
  float* S            = (float*)alloc((size_t)B_ * 16 * SMAX_ * 4);
  unsigned short* p   = (unsigned short*)alloc((size_t)B_ * 16 * SMAX_ * 2);
  float* pcls         = (float*)alloc((size_t)B_ * 16 * 4);
  unsigned short* u   = (unsigned short*)alloc((size_t)B_ * 16 * 1024 * 2);
  float* sm_cls = (float*)alloc((size_t)B_ * SM_ * 4);
  float* lg_cls = (float*)alloc((size_t)B_ * LG_ * 4);
  float* xbuf   = (float*)alloc((size_t)B_ * 1024 * 4);
  float* xnbuf  = (float*)alloc((size_t)B_ * 1024 * 4);
  float* qbuf   = (float*)alloc((size_t)B_ * 1024 * 4);
  float* kvc    = (float*)alloc((size_t)B_ * 2048 * 4);
  float* obuf   = (float*)alloc((size_t)B_ * 1024 * 4);
  float* t1     = (float*)alloc((size_t)B_ * 1024 * 4);
  (void)ws_size; (void)in_sizes; (void)n_in; (void)out_size;

  A.Abf = Abf_lg; A.xT = xT_lg;
  A.WTkv = WTkv_a; A.WTpin = WTpin_a; A.WTwq = WTwq_a; A.WTwo = WTwo_a; A.WTpout = WTpout_a;
  Bp.Abf = Abf_sm; Bp.xT = xT_sm;
  Bp.WTkv = WTkv_b; Bp.WTpin = WTpin_b; Bp.WTwq = WTwq_b; Bp.WTwo = WTwo_b; Bp.WTpout = WTpout_b;

  const size_t sm_elems = (size_t)B_ * (NSM_ + 1) * SM_;
  const size_t lg_elems = (size_t)B_ * (NLG_ + 1) * LG_;

  // output patches (cls rows overwritten at the end)
  copy_f32v4<<<2048, 256, 0, stream>>>(sm_tokens, out, (int)(sm_elems / 4));
  copy_f32v4<<<2048, 256, 0, stream>>>(lg_tokens, out + sm_elems, (int)(lg_elems / 4));
  // cls gather
  copy_rows<<<dim3(2, B_), 256, 0, stream>>>(sm_tokens, (size_t)(NSM_ + 1) * SM_, sm_cls, SM_, SM_);
  copy_rows<<<dim3(2, B_), 256, 0, stream>>>(lg_tokens, (size_t)(NLG_ + 1) * LG_, lg_cls, LG_, LG_);
  // patches -> bf16
  patches_to_bf16<<<dim3(128, B_), 256, 0, stream>>>(lg_tokens, Abf_lg, NLG_, LG_);
  patches_to_bf16<<<dim3(128, B_), 256, 0, stream>>>(sm_tokens, Abf_sm, NSM_, SM_);
  // x^T with zero pad
  transpose_x<<<dim3(LG_ / 64, 4, B_), dim3(64, 4), 0, stream>>>(Abf_lg, xT_lg, NLG_, LG_, 224);
  transpose_x<<<dim3(SM_ / 64, 7, B_), dim3(64, 4), 0, stream>>>(Abf_sm, xT_sm, NSM_, SM_, 416);
  // weight transposes (f32 -> bf16, (K,N)->(N,K), 4 layers each)
  transpose_to_bf16<<<dim3(2048/64, LG_/64, 4), dim3(64,4), 0, stream>>>(A.wkv,  WTkv_a, LG_, 2048);
  transpose_to_bf16<<<dim3(2048/64, SM_/64, 4), dim3(64,4), 0, stream>>>(Bp.wkv, WTkv_b, SM_, 2048);
  transpose_to_bf16<<<dim3(LG_/64, SM_/64, 4), dim3(64,4), 0, stream>>>(A.pin_w,  WTpin_a, SM_, LG_);
  transpose_to_bf16<<<dim3(SM_/64, LG_/64, 4), dim3(64,4), 0, stream>>>(Bp.pin_w, WTpin_b, LG_, SM_);
  transpose_to_bf16<<<dim3(INNER_/64, LG_/64, 4), dim3(64,4), 0, stream>>>(A.wq,  WTwq_a, LG_, INNER_);
  transpose_to_bf16<<<dim3(INNER_/64, SM_/64, 4), dim3(64,4), 0, stream>>>(Bp.wq, WTwq_b, SM_, INNER_);
  transpose_to_bf16<<<dim3(LG_/64, INNER_/64, 4), dim3(64,4), 0, stream>>>(A.wo,  WTwo_a, INNER_, LG_);
  transpose_to_bf16<<<dim3(SM_/64, INNER_/64, 4), dim3(64,4), 0, stream>>>(Bp.wo, WTwo_b, INNER_, SM_);
  transpose_to_bf16<<<dim3(SM_/64, LG_/64, 4), dim3(64,4), 0, stream>>>(A.pout_w,  WTpout_a, LG_, SM_);
  transpose_to_bf16<<<dim3(LG_/64, SM_/64, 4), dim3(64,4), 0, stream>>>(Bp.pout_w, WTpout_b, SM_, LG_);

  for (int i = 0; i < 4; i++) {
    run_step(stream, i, sm_cls, A, xbuf, xnbuf, qbuf, kvc, obuf, t1, qt, S, p, pcls, u);
    run_step(stream, i, lg_cls, Bp, xbuf, xnbuf, qbuf, kvc, obuf, t1, qt, S, p, pcls, u);
  }

  // final cls rows
  copy_rows<<<dim3(2, B_), 256, 0, stream>>>(sm_cls, SM_, out, (size_t)(NSM_ + 1) * SM_, SM_);
  copy_rows<<<dim3(2, B_), 256, 0, stream>>>(lg_cls, LG_, out + sm_elems, (size_t)(NLG_ + 1) * LG_, LG_);
}

// Round 3
// 1162.762 us; speedup vs baseline: 3.5226x; 1.9865x over previous
//
#include <hip/hip_runtime.h>
#include <hip/hip_bf16.h>
#include <math.h>

#define B_     64
#define NSM_   400
#define NLG_   196
#define SM_    512
#define LG_    1024
#define H_     16
#define DH_    64
#define INNER_ 1024

typedef __attribute__((ext_vector_type(8))) short bf16x8;
typedef __attribute__((ext_vector_type(4))) float f32x4;

__device__ __forceinline__ unsigned short f2b(float f) {
  unsigned u = __float_as_uint(f);
  u = u + 0x7FFFu + ((u >> 16) & 1u);   // RNE
  return (unsigned short)(u >> 16);
}

// ============================ setup kernels ================================

// one pass over tokens: full f32 copy to out, patches->bf16, cls row -> f32+bf16
struct CCArgs {
  const float* tok; float* out; unsigned short* abf; float* cls; unsigned short* clsb;
  int Np1, dim, nblk;
};
__global__ __launch_bounds__(256) void copy_cvt(CCArgs Aa, CCArgs Bb) {
  CCArgs g; int bx;
  if ((int)blockIdx.x < Aa.nblk) { g = Aa; bx = blockIdx.x; }
  else { g = Bb; bx = blockIdx.x - Aa.nblk; }
  int b = bx / g.Np1, row = bx % g.Np1;
  int t = threadIdx.x;
  int nf4 = g.dim >> 2;
  if (t >= nf4) return;
  const float4 v = ((const float4*)g.tok)[(size_t)bx * nf4 + t];
  ((float4*)g.out)[(size_t)bx * nf4 + t] = v;
  ushort4 w2;
  w2.x = f2b(v.x); w2.y = f2b(v.y); w2.z = f2b(v.z); w2.w = f2b(v.w);
  if (row > 0) {
    *(ushort4*)&g.abf[((size_t)b * (g.Np1 - 1) + row - 1) * g.dim + t * 4] = w2;
  } else {
    ((float4*)g.cls)[(size_t)b * nf4 + t] = v;
    *(ushort4*)&g.clsb[(size_t)b * g.dim + t * 4] = w2;
  }
}

// xbf [B*Nctx][dout] bf16 -> xT [B][dout][xstride] bf16, zero pad j>=Nctx
__global__ void transpose_x(const unsigned short* __restrict__ xbf,
                            unsigned short* __restrict__ xT,
                            int Nctx, int dout, int xstride) {
  __shared__ unsigned short tile[64][65];
  const int b = blockIdx.z;
  const int jt = blockIdx.y * 64, ct = blockIdx.x * 64;
  int tx = threadIdx.x, ty = threadIdx.y;  // (64,4)
  for (int r = ty; r < 64; r += 4) {
    int j = jt + r;
    tile[r][tx] = (j < Nctx) ? xbf[((size_t)b * Nctx + j) * dout + ct + tx]
                             : (unsigned short)0;
  }
  __syncthreads();
  for (int r = ty; r < 64; r += 4) {
    int col = jt + tx;
    if (col < xstride)
      xT[((size_t)b * dout + ct + r) * xstride + col] = tile[tx][r];
  }
}

// all 10 weight transposes (f32 (L,K,N) -> bf16 (L,N,K)) in one dispatch
struct WTDesc { const float* src; unsigned short* dst; int K, N; };
struct WTArgs { WTDesc d[10]; int cum[11]; };
__global__ __launch_bounds__(256) void wtrans_all(WTArgs W) {
  __shared__ unsigned short tile[64][65];
  int bx = blockIdx.x, di = 0;
  while (bx >= W.cum[di + 1]) di++;
  int local = bx - W.cum[di];
  WTDesc g = W.d[di];
  int tn = g.N >> 6;
  int tpl = tn * (g.K >> 6);
  int layer = local / tpl, rem = local % tpl;
  int kt = (rem / tn) * 64, nt = (rem % tn) * 64;
  const float* wp = g.src + (size_t)layer * g.K * g.N;
  unsigned short* op = g.dst + (size_t)layer * g.K * g.N;
  int tx = threadIdx.x & 63, ty = threadIdx.x >> 6;
  for (int r = ty; r < 64; r += 4)
    tile[r][tx] = f2b(wp[(size_t)(kt + r) * g.N + nt + tx]);
  __syncthreads();
  for (int r = ty; r < 64; r += 4)
    op[(size_t)(nt + r) * g.K + kt + tx] = tile[tx][r];
}

// ===================== merged-branch M=64 MFMA GEMM ========================
// modes: 0 = write f32; 1 = write bf16; 2 = f32 += in-place residual + bf16 mirror
struct GArgs {
  const unsigned short* A; const unsigned short* WT; const float* bias;
  float* Cf; unsigned short* Cbf; int K; int N; int ntiles;
};
__global__ __launch_bounds__(256) void dual_gemm(GArgs ga, GArgs gb, int mode) {
  GArgs g; int tile;
  if ((int)blockIdx.x < ga.ntiles) { g = ga; tile = blockIdx.x; }
  else { g = gb; tile = blockIdx.x - ga.ntiles; }
  const int t = threadIdx.x, lane = t & 63, w = t >> 6;
  const int n0 = tile * 64;
  const int r16 = lane & 15, kv8 = (lane >> 4) * 8;
  const int K = g.K, N = g.N;
  f32x4 acc[4];
#pragma unroll
  for (int nt2 = 0; nt2 < 4; nt2++) { acc[nt2][0]=0.f; acc[nt2][1]=0.f; acc[nt2][2]=0.f; acc[nt2][3]=0.f; }
  const unsigned short* ap = g.A + (size_t)(w * 16 + r16) * K + kv8;
#pragma unroll 4
  for (int k0 = 0; k0 < K; k0 += 32) {
    bf16x8 af = *(const bf16x8*)&ap[k0];
#pragma unroll
    for (int nt2 = 0; nt2 < 4; nt2++) {
      bf16x8 bfr = *(const bf16x8*)&g.WT[(size_t)(n0 + nt2 * 16 + r16) * K + k0 + kv8];
      acc[nt2] = __builtin_amdgcn_mfma_f32_16x16x32_bf16(af, bfr, acc[nt2], 0, 0, 0);
    }
  }
  const int rbase = (lane >> 4) * 4;
#pragma unroll
  for (int nt2 = 0; nt2 < 4; nt2++)
#pragma unroll
    for (int rr = 0; rr < 4; rr++) {
      int r = w * 16 + rbase + rr, c = n0 + nt2 * 16 + r16;
      float v = acc[nt2][rr];
      if (g.bias) v += g.bias[c];
      if (mode == 0) {
        g.Cf[(size_t)r * N + c] = v;
      } else if (mode == 1) {
        g.Cbf[(size_t)r * N + c] = f2b(v);
      } else {
        v += g.Cf[(size_t)r * N + c];
        g.Cf[(size_t)r * N + c] = v;
        g.Cbf[(size_t)r * N + c] = f2b(v);
      }
    }
}

// merged wq+wkv GEMM: N=3072 per branch (cols 0..1023 -> q f32, 1024.. -> kv f32)
struct QKVArgs {
  const unsigned short* A; const unsigned short* WTq; const unsigned short* WTkv;
  float* q; float* kv; int K; int ntiles;
};
__global__ __launch_bounds__(256) void qkv_gemm(QKVArgs ga, QKVArgs gb) {
  QKVArgs g; int tile;
  if ((int)blockIdx.x < ga.ntiles) { g = ga; tile = blockIdx.x; }
  else { g = gb; tile = blockIdx.x - ga.ntiles; }
  const int t = threadIdx.x, lane = t & 63, w = t >> 6;
  int n0 = tile * 64;
  const unsigned short* WT; float* C; int ldc, nb;
  if (n0 < 1024) { WT = g.WTq;  C = g.q;  ldc = 1024; nb = n0; }
  else           { WT = g.WTkv; C = g.kv; ldc = 2048; nb = n0 - 1024; }
  const int r16 = lane & 15, kv8 = (lane >> 4) * 8;
  const int K = g.K;
  f32x4 acc[4];
#pragma unroll
  for (int nt2 = 0; nt2 < 4; nt2++) { acc[nt2][0]=0.f; acc[nt2][1]=0.f; acc[nt2][2]=0.f; acc[nt2][3]=0.f; }
  const unsigned short* ap = g.A + (size_t)(w * 16 + r16) * K + kv8;
#pragma unroll 4
  for (int k0 = 0; k0 < K; k0 += 32) {
    bf16x8 af = *(const bf16x8*)&ap[k0];
#pragma unroll
    for (int nt2 = 0; nt2 < 4; nt2++) {
      bf16x8 bfr = *(const bf16x8*)&WT[(size_t)(nb + nt2 * 16 + r16) * K + k0 + kv8];
      acc[nt2] = __builtin_amdgcn_mfma_f32_16x16x32_bf16(af, bfr, acc[nt2], 0, 0, 0);
    }
  }
  const int rbase = (lane >> 4) * 4;
#pragma unroll
  for (int nt2 = 0; nt2 < 4; nt2++)
#pragma unroll
    for (int rr = 0; rr < 4; rr++)
      C[(size_t)(w * 16 + rbase + rr) * ldc + nb + nt2 * 16 + r16] = acc[nt2][rr];
}

// =============================== layernorm =================================
struct LNArgs { const float* x; unsigned short* xnb; const float* ng; const float* nb; int dim; };
__global__ __launch_bounds__(256) void ln2(LNArgs la, LNArgs lb) {
  LNArgs g = ((int)blockIdx.x < 64) ? la : lb;
  int b = blockIdx.x & 63, t = threadIdx.x;
  __shared__ float rs[4], rq[4], bc[2];
  const float* xp = g.x + (size_t)b * g.dim;
  float s = 0.f, sq = 0.f;
  for (int c = t; c < g.dim; c += 256) {
    float v = xp[c];
    s += v; sq += v * v;
  }
#pragma unroll
  for (int off = 32; off >= 1; off >>= 1) {
    s += __shfl_down(s, off);
    sq += __shfl_down(sq, off);
  }
  int w = t >> 6;
  if ((t & 63) == 0) { rs[w] = s; rq[w] = sq; }
  __syncthreads();
  if (t == 0) {
    float ts = rs[0] + rs[1] + rs[2] + rs[3];
    float tq = rq[0] + rq[1] + rq[2] + rq[3];
    float mu = ts / g.dim;
    float var = tq / g.dim - mu * mu;
    bc[0] = mu; bc[1] = rsqrtf(var + 1e-5f);
  }
  __syncthreads();
  float mu = bc[0], r = bc[1];
  for (int c = t; c < g.dim; c += 256)
    g.xnb[(size_t)b * g.dim + c] = f2b((xp[c] - mu) * r * g.ng[c] + g.nb[c]);
}

// ============================ q~ (merged) ==================================
// qt[b][h][c] = bf16( sum_d q[b][h*64+d] * wkv[c][h*64+d] )
__global__ __launch_bounds__(256) void qtilde2(const float* qa, const float* wkva,
                                               unsigned short* qta, int nxa,
                                               const float* qb, const float* wkvb,
                                               unsigned short* qtb) {
  const float* qbuf; const float* wkv; unsigned short* qt; int dout, ct;
  if ((int)blockIdx.x < nxa) { qbuf = qa; wkv = wkva; qt = qta; dout = 1024; ct = blockIdx.x; }
  else { qbuf = qb; wkv = wkvb; qt = qtb; dout = 512; ct = blockIdx.x - nxa; }
  const int h = blockIdx.y;
  __shared__ float qs[64][64];
  __shared__ float wsm[64][65];
  int t = threadIdx.x;
  for (int i = t; i < 64 * 64; i += 256) {
    int b = i >> 6, d = i & 63;
    qs[b][d] = qbuf[(size_t)b * INNER_ + h * 64 + d];
  }
  for (int i = t; i < 64 * 64; i += 256) {
    int c = i >> 6, d = i & 63;
    wsm[c][d] = wkv[(size_t)(ct * 64 + c) * 2048 + h * 64 + d];
  }
  __syncthreads();
  int b = t & 63, w = t >> 6;
  for (int c = w; c < 64; c += 4) {
    float s = 0.f;
#pragma unroll
    for (int d = 0; d < 64; d++) s += qs[b][d] * wsm[c][d];
    qt[((size_t)b * 16 + h) * dout + ct * 64 + c] = f2b(s);
  }
}

// ===================== fused attention (s + softmax + u) ===================
#define QSTR 1032
#define SSTR 424
struct FAArgs {
  const unsigned short* xbf; const unsigned short* xT; const unsigned short* qt;
  const float* qb; const float* kvc; unsigned short* u; float* pcls;
  int dout, Nctx, Npad, xstride, ldq;
};
__global__ __launch_bounds__(512) void fused_attn(FAArgs Aa, FAArgs Bb) {
  __shared__ unsigned short qt_s[16 * QSTR];
  __shared__ float S_s[16 * SSTR];
  __shared__ unsigned short p_s[16 * SSTR];
  const int br = blockIdx.x >> 6, b = blockIdx.x & 63;
  FAArgs g = br ? Bb : Aa;
  const int t = threadIdx.x, lane = t & 63, w = t >> 6;
  const int dout = g.dout;
  // stage q~ into LDS (padded stride)
  for (int i = t * 8; i < 16 * dout; i += 512 * 8) {
    int h = i >> g.ldq, c = i & (dout - 1);
    *(bf16x8*)&qt_s[h * QSTR + c] = *(const bf16x8*)&g.qt[((size_t)b * 16 + h) * dout + c];
  }
  __syncthreads();
  const int r16 = lane & 15, kv8 = (lane >> 4) * 8, rbase = (lane >> 4) * 4;
  // ---- s-phase: S[h][j] = q~[h,:] . x[j,:]
  const int NTj = g.Npad >> 4;
  for (int jt = w; jt < NTj; jt += 8) {
    f32x4 acc; acc[0]=0.f; acc[1]=0.f; acc[2]=0.f; acc[3]=0.f;
    const unsigned short* bp = g.xbf + ((size_t)b * g.Nctx + jt * 16 + r16) * dout + kv8;
    const unsigned short* apl = &qt_s[r16 * QSTR + kv8];
#pragma unroll 4
    for (int k0 = 0; k0 < dout; k0 += 32) {
      bf16x8 af = *(const bf16x8*)&apl[k0];
      bf16x8 bfr = *(const bf16x8*)&bp[k0];
      acc = __builtin_amdgcn_mfma_f32_16x16x32_bf16(af, bfr, acc, 0, 0, 0);
    }
#pragma unroll
    for (int rr = 0; rr < 4; rr++)
      S_s[(rbase + rr) * SSTR + jt * 16 + r16] = acc[rr];
  }
  __syncthreads();
  // ---- softmax (wave w handles rows 2w, 2w+1)
  for (int h = w * 2; h < w * 2 + 2; h++) {
    float sc = g.qb[(size_t)b * 1024 + h * 64 + lane] * g.kvc[(size_t)b * 2048 + h * 64 + lane];
#pragma unroll
    for (int o = 32; o >= 1; o >>= 1) sc += __shfl_down(sc, o);
    sc = __shfl(sc, 0) * 0.125f;
    float mr = -1e30f;
    for (int j = lane; j < g.Nctx; j += 64) mr = fmaxf(mr, S_s[h * SSTR + j]);
#pragma unroll
    for (int o = 32; o >= 1; o >>= 1) mr = fmaxf(mr, __shfl_down(mr, o));
    mr = __shfl(mr, 0);
    const float m = fmaxf(mr * 0.125f, sc);
    float es = 0.f;
    for (int j = lane; j < g.Nctx; j += 64) {
      float e = expf(S_s[h * SSTR + j] * 0.125f - m);
      S_s[h * SSTR + j] = e;
      es += e;
    }
#pragma unroll
    for (int o = 32; o >= 1; o >>= 1) es += __shfl_down(es, o);
    es = __shfl(es, 0);
    const float ecls = expf(sc - m);
    const float inv = 1.f / (es + ecls);
    for (int j = lane; j < g.Npad; j += 64)
      p_s[h * SSTR + j] = (j < g.Nctx) ? f2b(S_s[h * SSTR + j] * inv) : (unsigned short)0;
    if (lane == 0) g.pcls[b * 16 + h] = ecls * inv;
  }
  __syncthreads();
  // ---- u-phase: u[h][c] = p[h,:] . xT[c,:]
  const int NTc = dout >> 4;
  for (int ct = w; ct < NTc; ct += 8) {
    f32x4 acc; acc[0]=0.f; acc[1]=0.f; acc[2]=0.f; acc[3]=0.f;
    const unsigned short* bp = g.xT + ((size_t)b * dout + ct * 16 + r16) * g.xstride + kv8;
    const unsigned short* apl = &p_s[r16 * SSTR + kv8];
#pragma unroll 4
    for (int k0 = 0; k0 < g.Npad; k0 += 32) {
      bf16x8 af = *(const bf16x8*)&apl[k0];
      bf16x8 bfr = *(const bf16x8*)&bp[k0];
      acc = __builtin_amdgcn_mfma_f32_16x16x32_bf16(af, bfr, acc, 0, 0, 0);
    }
#pragma unroll
    for (int rr = 0; rr < 4; rr++)
      g.u[((size_t)b * 16 + rbase + rr) * dout + ct * 16 + r16] = f2b(acc[rr]);
  }
}

// ============================ o = u.Wv (merged) ============================
struct OArgs {
  const unsigned short* u; const unsigned short* WTkv; const float* kvc; const float* pcls;
  unsigned short* ob; int dout;
};
__global__ __launch_bounds__(256) void ogemm2(OArgs ga, OArgs gb) {
  OArgs g; int h;
  if ((int)blockIdx.x < 16) { g = ga; h = blockIdx.x; }
  else { g = gb; h = blockIdx.x - 16; }
  const int t = threadIdx.x, lane = t & 63, w = t >> 6;
  const int r16 = lane & 15, kv8 = (lane >> 4) * 8;
  const int dout = g.dout;
  const unsigned short* ap = g.u + ((size_t)(w * 16 + r16) * 16 + h) * dout + kv8;
  f32x4 acc[4];
#pragma unroll
  for (int nt2 = 0; nt2 < 4; nt2++) { acc[nt2][0]=0.f; acc[nt2][1]=0.f; acc[nt2][2]=0.f; acc[nt2][3]=0.f; }
#pragma unroll 4
  for (int k0 = 0; k0 < dout; k0 += 32) {
    bf16x8 af = *(const bf16x8*)&ap[k0];
#pragma unroll
    for (int nt2 = 0; nt2 < 4; nt2++) {
      bf16x8 bfr = *(const bf16x8*)&g.WTkv[(size_t)(1024 + h * 64 + nt2 * 16 + r16) * dout + k0 + kv8];
      acc[nt2] = __builtin_amdgcn_mfma_f32_16x16x32_bf16(af, bfr, acc[nt2], 0, 0, 0);
    }
  }
  const int rbase = (lane >> 4) * 4;
#pragma unroll
  for (int nt2 = 0; nt2 < 4; nt2++)
#pragma unroll
    for (int rr = 0; rr < 4; rr++) {
      int bi = w * 16 + rbase + rr;
      int d = h * 64 + nt2 * 16 + r16;
      float v = acc[nt2][rr] + g.pcls[bi * 16 + h] * g.kvc[(size_t)bi * 2048 + 1024 + d];
      g.ob[(size_t)bi * INNER_ + d] = f2b(v);
    }
}

// ============================ final cls copy ===============================
__global__ __launch_bounds__(256) void final_copy(const float* clsa, float* outa, int Np1a, int dima,
                                                  const float* clsb2, float* outb, int Np1b, int dimb) {
  int x = blockIdx.x, t = threadIdx.x;
  if (x < 64) {
    for (int c = t; c < dima; c += 256)
      outa[(size_t)x * Np1a * dima + c] = clsa[(size_t)x * dima + c];
  } else {
    int b = x - 64;
    for (int c = t; c < dimb; c += 256)
      outb[(size_t)b * Np1b * dimb + c] = clsb2[(size_t)b * dimb + c];
  }
}

// ================================ host =====================================
extern "C" void kernel_launch(void* const* d_in, const int* in_sizes, int n_in,
                              void* d_out, int out_size, void* d_ws, size_t ws_size,
                              hipStream_t stream) {
  const float* sm_tokens = (const float*)d_in[0];
  const float* lg_tokens = (const float*)d_in[1];
  const float* a_pin_w  = (const float*)d_in[2];  const float* a_pin_b  = (const float*)d_in[3];
  const float* a_ng     = (const float*)d_in[4];  const float* a_nb     = (const float*)d_in[5];
  const float* a_wq     = (const float*)d_in[6];  const float* a_wkv    = (const float*)d_in[7];
  const float* a_wo     = (const float*)d_in[8];  const float* a_wob    = (const float*)d_in[9];
  const float* a_pout_w = (const float*)d_in[10]; const float* a_pout_b = (const float*)d_in[11];
  const float* b_pin_w  = (const float*)d_in[12]; const float* b_pin_b  = (const float*)d_in[13];
  const float* b_ng     = (const float*)d_in[14]; const float* b_nb     = (const float*)d_in[15];
  const float* b_wq     = (const float*)d_in[16]; const float* b_wkv    = (const float*)d_in[17];
  const float* b_wo     = (const float*)d_in[18]; const float* b_wob    = (const float*)d_in[19];
  const float* b_pout_w = (const float*)d_in[20]; const float* b_pout_b = (const float*)d_in[21];

  float* out = (float*)d_out;
  char* ws = (char*)d_ws;
  size_t off = 0;
  auto alloc = [&](size_t bytes) -> void* {
    void* pt = ws + off;
    off += (bytes + 255) & ~(size_t)255;
    return pt;
  };
  unsigned short* Abf_lg = (unsigned short*)alloc(((size_t)B_ * NLG_ + 32) * LG_ * 2);
  unsigned short* Abf_sm = (unsigned short*)alloc(((size_t)B_ * NSM_ + 32) * SM_ * 2);
  unsigned short* xT_lg  = (unsigned short*)alloc((size_t)B_ * LG_ * 224 * 2);
  unsigned short* xT_sm  = (unsigned short*)alloc((size_t)B_ * SM_ * 416 * 2);
  unsigned short* WTkv_a = (unsigned short*)alloc((size_t)4 * 2048 * LG_ * 2);
  unsigned short* WTkv_b = (unsigned short*)alloc((size_t)4 * 2048 * SM_ * 2);
  unsigned short* WTpin_a = (unsigned short*)alloc((size_t)4 * SM_ * LG_ * 2);
  unsigned short* WTpin_b = (unsigned short*)alloc((size_t)4 * LG_ * SM_ * 2);
  unsigned short* WTwq_a  = (unsigned short*)alloc((size_t)4 * LG_ * INNER_ * 2);
  unsigned short* WTwq_b  = (unsigned short*)alloc((size_t)4 * SM_ * INNER_ * 2);
  unsigned short* WTwo_a  = (unsigned short*)alloc((size_t)4 * INNER_ * LG_ * 2);
  unsigned short* WTwo_b  = (unsigned short*)alloc((size_t)4 * INNER_ * SM_ * 2);
  unsigned short* WTpout_a = (unsigned short*)alloc((size_t)4 * LG_ * SM_ * 2);
  unsigned short* WTpout_b = (unsigned short*)alloc((size_t)4 * SM_ * LG_ * 2);
  unsigned short* qt_a = (unsigned short*)alloc((size_t)B_ * 16 * LG_ * 2);
  unsigned short* qt_b = (unsigned short*)alloc((size_t)B_ * 16 * SM_ * 2);
  unsigned short* u_a  = (unsigned short*)alloc((size_t)B_ * 16 * LG_ * 2);
  unsigned short* u_b  = (unsigned short*)alloc((size_t)B_ * 16 * SM_ * 2);
  float* pcls_a = (float*)alloc((size_t)B_ * 16 * 4);
  float* pcls_b = (float*)alloc((size_t)B_ * 16 * 4);
  float* cls_sm = (float*)alloc((size_t)B_ * SM_ * 4);
  float* cls_lg = (float*)alloc((size_t)B_ * LG_ * 4);
  unsigned short* clsb_sm = (unsigned short*)alloc((size_t)B_ * SM_ * 2);
  unsigned short* clsb_lg = (unsigned short*)alloc((size_t)B_ * LG_ * 2);
  float* xbuf_a = (float*)alloc((size_t)B_ * LG_ * 4);
  float* xbuf_b = (float*)alloc((size_t)B_ * SM_ * 4);
  unsigned short* xnb_a = (unsigned short*)alloc((size_t)B_ * LG_ * 2);
  unsigned short* xnb_b = (unsigned short*)alloc((size_t)B_ * SM_ * 2);
  float* qbuf_a = (float*)alloc((size_t)B_ * INNER_ * 4);
  float* qbuf_b = (float*)alloc((size_t)B_ * INNER_ * 4);
  float* kvc_a  = (float*)alloc((size_t)B_ * 2048 * 4);
  float* kvc_b  = (float*)alloc((size_t)B_ * 2048 * 4);
  unsigned short* obufb_a = (unsigned short*)alloc((size_t)B_ * INNER_ * 2);
  unsigned short* obufb_b = (unsigned short*)alloc((size_t)B_ * INNER_ * 2);
  unsigned short* t1b_a = (unsigned short*)alloc((size_t)B_ * LG_ * 2);
  unsigned short* t1b_b = (unsigned short*)alloc((size_t)B_ * SM_ * 2);
  (void)ws_size; (void)in_sizes; (void)n_in; (void)out_size;

  const size_t sm_elems = (size_t)B_ * (NSM_ + 1) * SM_;

  // ---- setup: tokens pass
  CCArgs ca{sm_tokens, out, Abf_sm, cls_sm, clsb_sm, NSM_ + 1, SM_, B_ * (NSM_ + 1)};
  CCArgs cb{lg_tokens, out + sm_elems, Abf_lg, cls_lg, clsb_lg, NLG_ + 1, LG_, B_ * (NLG_ + 1)};
  copy_cvt<<<ca.nblk + cb.nblk, 256, 0, stream>>>(ca, cb);
  transpose_x<<<dim3(LG_ / 64, 4, B_), dim3(64, 4), 0, stream>>>(Abf_lg, xT_lg, NLG_, LG_, 224);
  transpose_x<<<dim3(SM_ / 64, 7, B_), dim3(64, 4), 0, stream>>>(Abf_sm, xT_sm, NSM_, SM_, 416);
  // ---- setup: all weight transposes
  WTArgs W;
  W.d[0] = {a_wkv,    WTkv_a,   LG_, 2048};
  W.d[1] = {b_wkv,    WTkv_b,   SM_, 2048};
  W.d[2] = {a_pin_w,  WTpin_a,  SM_, LG_};
  W.d[3] = {b_pin_w,  WTpin_b,  LG_, SM_};
  W.d[4] = {a_wq,     WTwq_a,   LG_, INNER_};
  W.d[5] = {b_wq,     WTwq_b,   SM_, INNER_};
  W.d[6] = {a_wo,     WTwo_a,   INNER_, LG_};
  W.d[7] = {b_wo,     WTwo_b,   INNER_, SM_};
  W.d[8] = {a_pout_w, WTpout_a, LG_, SM_};
  W.d[9] = {b_pout_w, WTpout_b, SM_, LG_};
  W.cum[0] = 0;
  for (int i = 0; i < 10; i++)
    W.cum[i + 1] = W.cum[i] + (W.d[i].K / 64) * (W.d[i].N / 64) * 4;
  wtrans_all<<<W.cum[10], 256, 0, stream>>>(W);

  for (int l = 0; l < 4; l++) {
    // per-layer weight pointers
    const unsigned short* WTpin_al = WTpin_a + (size_t)l * SM_ * LG_;
    const unsigned short* WTpin_bl = WTpin_b + (size_t)l * LG_ * SM_;
    const unsigned short* WTwq_al  = WTwq_a  + (size_t)l * LG_ * INNER_;
    const unsigned short* WTwq_bl  = WTwq_b  + (size_t)l * SM_ * INNER_;
    const unsigned short* WTkv_al  = WTkv_a  + (size_t)l * 2048 * LG_;
    const unsigned short* WTkv_bl  = WTkv_b  + (size_t)l * 2048 * SM_;
    const unsigned short* WTwo_al  = WTwo_a  + (size_t)l * INNER_ * LG_;
    const unsigned short* WTwo_bl  = WTwo_b  + (size_t)l * INNER_ * SM_;
    const unsigned short* WTpout_al = WTpout_a + (size_t)l * LG_ * SM_;
    const unsigned short* WTpout_bl = WTpout_b + (size_t)l * SM_ * LG_;

    // pin
    GArgs pa{clsb_sm, WTpin_al, a_pin_b + (size_t)l * LG_, xbuf_a, nullptr, SM_, LG_, LG_ / 64};
    GArgs pb{clsb_lg, WTpin_bl, b_pin_b + (size_t)l * SM_, xbuf_b, nullptr, LG_, SM_, SM_ / 64};
    dual_gemm<<<pa.ntiles + pb.ntiles, 256, 0, stream>>>(pa, pb, 0);
    // ln
    LNArgs la{xbuf_a, xnb_a, a_ng + (size_t)l * LG_, a_nb + (size_t)l * LG_, LG_};
    LNArgs lb{xbuf_b, xnb_b, b_ng + (size_t)l * SM_, b_nb + (size_t)l * SM_, SM_};
    ln2<<<128, 256, 0, stream>>>(la, lb);
    // q + kv (cls)
    QKVArgs qa{xnb_a, WTwq_al, WTkv_al, qbuf_a, kvc_a, LG_, 48};
    QKVArgs qb{xnb_b, WTwq_bl, WTkv_bl, qbuf_b, kvc_b, SM_, 48};
    qkv_gemm<<<96, 256, 0, stream>>>(qa, qb);
    // q~
    qtilde2<<<dim3(24, 16), 256, 0, stream>>>(qbuf_a, a_wkv + (size_t)l * LG_ * 2048, qt_a, 16,
                                              qbuf_b, b_wkv + (size_t)l * SM_ * 2048, qt_b);
    // fused attention
    FAArgs fa{Abf_lg, xT_lg, qt_a, qbuf_a, kvc_a, u_a, pcls_a, LG_, NLG_, 224, 224, 10};
    FAArgs fb{Abf_sm, xT_sm, qt_b, qbuf_b, kvc_b, u_b, pcls_b, SM_, NSM_, 416, 416, 9};
    fused_attn<<<128, 512, 0, stream>>>(fa, fb);
    // o = u.Wv + pcls*vcls
    OArgs oa{u_a, WTkv_al, kvc_a, pcls_a, obufb_a, LG_};
    OArgs ob{u_b, WTkv_bl, kvc_b, pcls_b, obufb_b, SM_};
    ogemm2<<<32, 256, 0, stream>>>(oa, ob);
    // wo
    GArgs wa{obufb_a, WTwo_al, a_wob + (size_t)l * LG_, nullptr, t1b_a, INNER_, LG_, LG_ / 64};
    GArgs wb{obufb_b, WTwo_bl, b_wob + (size_t)l * SM_, nullptr, t1b_b, INNER_, SM_, SM_ / 64};
    dual_gemm<<<wa.ntiles + wb.ntiles, 256, 0, stream>>>(wa, wb, 1);
    // pout + residual
    GArgs ra{t1b_a, WTpout_al, a_pout_b + (size_t)l * SM_, cls_sm, clsb_sm, LG_, SM_, SM_ / 64};
    GArgs rb{t1b_b, WTpout_bl, b_pout_b + (size_t)l * LG_, cls_lg, clsb_lg, SM_, LG_, LG_ / 64};
    dual_gemm<<<ra.ntiles + rb.ntiles, 256, 0, stream>>>(ra, rb, 2);
  }

  final_copy<<<128, 256, 0, stream>>>(cls_sm, out, NSM_ + 1, SM_,
                                      cls_lg, out + sm_elems, NLG_ + 1, LG_);
}

// Round 4
// 1044.054 us; speedup vs baseline: 3.9231x; 1.1137x over previous
//
#include <hip/hip_runtime.h>
#include <hip/hip_bf16.h>
#include <math.h>

#define B_     64
#define NSM_   400
#define NLG_   196
#define SM_    512
#define LG_    1024
#define H_     16
#define DH_    64
#define INNER_ 1024
#define SSTR   424    // row stride for S (f32) and p (bf16 in LDS)
#define NJMAX  7

typedef __attribute__((ext_vector_type(8))) short bf16x8;
typedef __attribute__((ext_vector_type(4))) float f32x4;

__device__ __forceinline__ unsigned short f2b(float f) {
  unsigned u = __float_as_uint(f);
  u = u + 0x7FFFu + ((u >> 16) & 1u);   // RNE
  return (unsigned short)(u >> 16);
}

// ============================ setup kernels ================================

// one pass over tokens: full f32 copy to out, patches->bf16, cls row -> f32+bf16
struct CCArgs {
  const float* tok; float* out; unsigned short* abf; float* cls; unsigned short* clsb;
  int Np1, dim, nblk;
};
__global__ __launch_bounds__(256) void copy_cvt(CCArgs Aa, CCArgs Bb) {
  CCArgs g; int bx;
  if ((int)blockIdx.x < Aa.nblk) { g = Aa; bx = blockIdx.x; }
  else { g = Bb; bx = blockIdx.x - Aa.nblk; }
  int b = bx / g.Np1, row = bx % g.Np1;
  int t = threadIdx.x;
  int nf4 = g.dim >> 2;
  if (t >= nf4) return;
  const float4 v = ((const float4*)g.tok)[(size_t)bx * nf4 + t];
  ((float4*)g.out)[(size_t)bx * nf4 + t] = v;
  ushort4 w2;
  w2.x = f2b(v.x); w2.y = f2b(v.y); w2.z = f2b(v.z); w2.w = f2b(v.w);
  if (row > 0) {
    *(ushort4*)&g.abf[((size_t)b * (g.Np1 - 1) + row - 1) * g.dim + t * 4] = w2;
  } else {
    ((float4*)g.cls)[(size_t)b * nf4 + t] = v;
    *(ushort4*)&g.clsb[(size_t)b * g.dim + t * 4] = w2;
  }
}

// xbf [B*Nctx][dout] bf16 -> xT [B][dout][xstride] bf16, zero pad j>=Nctx (both branches)
struct TXArgs { const unsigned short* xbf; unsigned short* xT; int Nctx, dout, xstride, nx, ny, nblk; };
__global__ void transpose_x2(TXArgs ga, TXArgs gb) {
  __shared__ unsigned short tile[64][65];
  TXArgs g; int bx;
  if ((int)blockIdx.x < ga.nblk) { g = ga; bx = blockIdx.x; }
  else { g = gb; bx = blockIdx.x - ga.nblk; }
  int cx = bx % g.nx; int rem = bx / g.nx;
  int jy = rem % g.ny; int b = rem / g.ny;
  int jt = jy * 64, ct = cx * 64;
  int tx = threadIdx.x, ty = threadIdx.y;  // (64,4)
  for (int r = ty; r < 64; r += 4) {
    int j = jt + r;
    tile[r][tx] = (j < g.Nctx) ? g.xbf[((size_t)b * g.Nctx + j) * g.dout + ct + tx]
                               : (unsigned short)0;
  }
  __syncthreads();
  for (int r = ty; r < 64; r += 4) {
    int col = jt + tx;
    if (col < g.xstride)
      g.xT[((size_t)b * g.dout + ct + r) * g.xstride + col] = tile[tx][r];
  }
}

// all 10 weight transposes (f32 (L,K,N) -> bf16 (L,N,K)) in one dispatch
struct WTDesc { const float* src; unsigned short* dst; int K, N; };
struct WTArgs { WTDesc d[10]; int cum[11]; };
__global__ __launch_bounds__(256) void wtrans_all(WTArgs W) {
  __shared__ unsigned short tile[64][65];
  int bx = blockIdx.x, di = 0;
  while (bx >= W.cum[di + 1]) di++;
  int local = bx - W.cum[di];
  WTDesc g = W.d[di];
  int tn = g.N >> 6;
  int tpl = tn * (g.K >> 6);
  int layer = local / tpl, rem = local % tpl;
  int kt = (rem / tn) * 64, nt = (rem % tn) * 64;
  const float* wp = g.src + (size_t)layer * g.K * g.N;
  unsigned short* op = g.dst + (size_t)layer * g.K * g.N;
  int tx = threadIdx.x & 63, ty = threadIdx.x >> 6;
  for (int r = ty; r < 64; r += 4)
    tile[r][tx] = f2b(wp[(size_t)(kt + r) * g.N + nt + tx]);
  __syncthreads();
  for (int r = ty; r < 64; r += 4)
    op[(size_t)(nt + r) * g.K + kt + tx] = tile[tx][r];
}

// ================= wide small GEMM: M=64, one 16-col tile per 1-wave block =
struct SGDesc {
  const unsigned short* A;    // [64][K] bf16
  const unsigned short* WT;   // [N][K] bf16
  const float* bias;          // [N] or null
  float* Cf;                  // f32 out [64][N] or null
  unsigned short* Cbf;        // bf16 out [64][N] or null
  const float* Rf;            // residual f32 in [64][N] or null
  int K, N;
};
struct SGArgs { SGDesc d[4]; int cum[5]; int nd; };
__global__ __launch_bounds__(64) void sg_wide(SGArgs W) {
  int bx = blockIdx.x, di = 0;
  while (di < W.nd - 1 && bx >= W.cum[di + 1]) di++;
  SGDesc g = W.d[di];
  const int n0 = (bx - W.cum[di]) * 16;
  const int lane = threadIdx.x, r16 = lane & 15, kv8 = (lane >> 4) * 8;
  f32x4 acc[4];
#pragma unroll
  for (int mt = 0; mt < 4; mt++) { acc[mt][0]=0.f; acc[mt][1]=0.f; acc[mt][2]=0.f; acc[mt][3]=0.f; }
  const unsigned short* wp = &g.WT[(size_t)(n0 + r16) * g.K + kv8];
  const unsigned short* ap0 = &g.A[(size_t)r16 * g.K + kv8];
  const int K = g.K;
#pragma unroll 2
  for (int k0 = 0; k0 < K; k0 += 32) {
    bf16x8 bfr = *(const bf16x8*)&wp[k0];
#pragma unroll
    for (int mt = 0; mt < 4; mt++) {
      bf16x8 af = *(const bf16x8*)&ap0[(size_t)mt * 16 * K + k0];
      acc[mt] = __builtin_amdgcn_mfma_f32_16x16x32_bf16(af, bfr, acc[mt], 0, 0, 0);
    }
  }
  const int rbase = (lane >> 4) * 4;
#pragma unroll
  for (int mt = 0; mt < 4; mt++)
#pragma unroll
    for (int rr = 0; rr < 4; rr++) {
      int r = mt * 16 + rbase + rr, c = n0 + r16;
      float v = acc[mt][rr];
      if (g.bias) v += g.bias[c];
      if (g.Rf) v += g.Rf[(size_t)r * g.N + c];
      if (g.Cf)  g.Cf[(size_t)r * g.N + c] = v;
      if (g.Cbf) g.Cbf[(size_t)r * g.N + c] = f2b(v);
    }
}

// =============================== layernorm =================================
struct LNArgs { const float* x; unsigned short* xnb; const float* ng; const float* nb; int dim; };
__global__ __launch_bounds__(256) void ln2(LNArgs la, LNArgs lb) {
  LNArgs g = ((int)blockIdx.x < 64) ? la : lb;
  int b = blockIdx.x & 63, t = threadIdx.x;
  __shared__ float rs[4], rq[4], bc[2];
  const float* xp = g.x + (size_t)b * g.dim;
  float s = 0.f, sq = 0.f;
  for (int c = t; c < g.dim; c += 256) {
    float v = xp[c];
    s += v; sq += v * v;
  }
#pragma unroll
  for (int off = 32; off >= 1; off >>= 1) {
    s += __shfl_down(s, off);
    sq += __shfl_down(sq, off);
  }
  int w = t >> 6;
  if ((t & 63) == 0) { rs[w] = s; rq[w] = sq; }
  __syncthreads();
  if (t == 0) {
    float ts = rs[0] + rs[1] + rs[2] + rs[3];
    float tq = rq[0] + rq[1] + rq[2] + rq[3];
    float mu = ts / g.dim;
    float var = tq / g.dim - mu * mu;
    bc[0] = mu; bc[1] = rsqrtf(var + 1e-5f);
  }
  __syncthreads();
  float mu = bc[0], r = bc[1];
  for (int c = t; c < g.dim; c += 256)
    g.xnb[(size_t)b * g.dim + c] = f2b((xp[c] - mu) * r * g.ng[c] + g.nb[c]);
}

// ============================ q~ (merged) ==================================
// qt[b][h][c] = bf16( sum_d q[b][h*64+d] * wkv[c][h*64+d] )
__global__ __launch_bounds__(256) void qtilde2(const float* qa, const float* wkva,
                                               unsigned short* qta, int nxa,
                                               const float* qb, const float* wkvb,
                                               unsigned short* qtb) {
  const float* qbuf; const float* wkv; unsigned short* qt; int dout, ct;
  if ((int)blockIdx.x < nxa) { qbuf = qa; wkv = wkva; qt = qta; dout = 1024; ct = blockIdx.x; }
  else { qbuf = qb; wkv = wkvb; qt = qtb; dout = 512; ct = blockIdx.x - nxa; }
  const int h = blockIdx.y;
  __shared__ float qs[64][64];
  __shared__ float wsm[64][65];
  int t = threadIdx.x;
  for (int i = t; i < 64 * 64; i += 256) {
    int b = i >> 6, d = i & 63;
    qs[b][d] = qbuf[(size_t)b * INNER_ + h * 64 + d];
  }
  for (int i = t; i < 64 * 64; i += 256) {
    int c = i >> 6, d = i & 63;
    wsm[c][d] = wkv[(size_t)(ct * 64 + c) * 2048 + h * 64 + d];
  }
  __syncthreads();
  int b = t & 63, w = t >> 6;
  for (int c = w; c < 64; c += 4) {
    float s = 0.f;
#pragma unroll
    for (int d = 0; d < 64; d++) s += qs[b][d] * wsm[c][d];
    qt[((size_t)b * 16 + h) * dout + ct * 64 + c] = f2b(s);
  }
}

// ======================== S = q~ . x^T (1 wave / 16x16 tile) ===============
struct SArgs { const unsigned short* qt; const unsigned short* xbf; float* S;
               int dout, Nctx, ntj, nblk; };
__global__ __launch_bounds__(64) void s_gemm(SArgs ga, SArgs gb) {
  SArgs g; int bx;
  if ((int)blockIdx.x < ga.nblk) { g = ga; bx = blockIdx.x; }
  else { g = gb; bx = blockIdx.x - ga.nblk; }
  const int b = bx / g.ntj, jt = bx - b * g.ntj;
  const int lane = threadIdx.x;
  const int r16 = lane & 15, kv8 = (lane >> 4) * 8;
  const unsigned short* ap = g.qt + ((size_t)b * 16 + r16) * g.dout + kv8;
  const unsigned short* bp = g.xbf + ((size_t)b * g.Nctx + jt * 16 + r16) * g.dout + kv8;
  f32x4 acc; acc[0]=0.f; acc[1]=0.f; acc[2]=0.f; acc[3]=0.f;
  const int K = g.dout;
#pragma unroll 4
  for (int k0 = 0; k0 < K; k0 += 32) {
    bf16x8 af = *(const bf16x8*)&ap[k0];
    bf16x8 bfr = *(const bf16x8*)&bp[k0];
    acc = __builtin_amdgcn_mfma_f32_16x16x32_bf16(af, bfr, acc, 0, 0, 0);
  }
  const int rbase = (lane >> 4) * 4;
#pragma unroll
  for (int rr = 0; rr < 4; rr++)
    g.S[((size_t)b * 16 + rbase + rr) * SSTR + jt * 16 + r16] = acc[rr];
}

// ================= softmax (redundant per block) + u = p . x ===============
struct UArgs {
  const float* S; const float* qb; const float* kvc; const unsigned short* xT;
  unsigned short* u; float* pcls; int dout, Nctx, Npad, xstride, ntc, nblk;
};
__global__ __launch_bounds__(256) void usoftmax(UArgs ga, UArgs gb) {
  __shared__ unsigned short p_s[16 * SSTR];
  UArgs g; int bx;
  if ((int)blockIdx.x < ga.nblk) { g = ga; bx = blockIdx.x; }
  else { g = gb; bx = blockIdx.x - ga.nblk; }
  const int b = bx / g.ntc, ct = bx - b * g.ntc;
  const int t = threadIdx.x, lane = t & 63, w = t >> 6;
  // ---- softmax: wave w handles heads w*4 .. w*4+3 (redundant across ct-blocks)
  for (int hh = 0; hh < 4; hh++) {
    const int h = w * 4 + hh;
    const float* Sp = g.S + ((size_t)b * 16 + h) * SSTR;
    float sc = g.qb[(size_t)b * 1024 + h * 64 + lane] * g.kvc[(size_t)b * 2048 + h * 64 + lane];
#pragma unroll
    for (int o = 32; o >= 1; o >>= 1) sc += __shfl_down(sc, o);
    sc = __shfl(sc, 0) * 0.125f;
    float sv[NJMAX];
    float mr = -1e30f;
#pragma unroll
    for (int ji = 0; ji < NJMAX; ji++) {
      int j = ji * 64 + lane;
      sv[ji] = (j < g.Nctx) ? Sp[j] * 0.125f : -1e30f;
      mr = fmaxf(mr, sv[ji]);
    }
#pragma unroll
    for (int o = 32; o >= 1; o >>= 1) mr = fmaxf(mr, __shfl_down(mr, o));
    mr = __shfl(mr, 0);
    const float m = fmaxf(mr, sc);
    float es = 0.f;
#pragma unroll
    for (int ji = 0; ji < NJMAX; ji++) {
      int j = ji * 64 + lane;
      float e = (j < g.Nctx) ? expf(sv[ji] - m) : 0.f;
      sv[ji] = e; es += e;
    }
#pragma unroll
    for (int o = 32; o >= 1; o >>= 1) es += __shfl_down(es, o);
    es = __shfl(es, 0);
    const float ecls = expf(sc - m);
    const float inv = 1.f / (es + ecls);
#pragma unroll
    for (int ji = 0; ji < NJMAX; ji++) {
      int j = ji * 64 + lane;
      if (j < g.Npad) p_s[h * SSTR + j] = (j < g.Nctx) ? f2b(sv[ji] * inv) : (unsigned short)0;
    }
    if (ct == 0 && lane == 0) g.pcls[b * 16 + h] = ecls * inv;
  }
  __syncthreads();
  // ---- u-phase: wave w computes 16-col subtile at ct*64 + w*16
  const int r16 = lane & 15, kv8 = (lane >> 4) * 8, rbase = (lane >> 4) * 4;
  const int c0 = ct * 64 + w * 16;
  f32x4 acc; acc[0]=0.f; acc[1]=0.f; acc[2]=0.f; acc[3]=0.f;
  const unsigned short* bp = g.xT + ((size_t)b * g.dout + c0 + r16) * g.xstride + kv8;
  const unsigned short* apl = &p_s[r16 * SSTR + kv8];
  const int Kp = g.Npad;
#pragma unroll 4
  for (int k0 = 0; k0 < Kp; k0 += 32) {
    bf16x8 af = *(const bf16x8*)&apl[k0];
    bf16x8 bfr = *(const bf16x8*)&bp[k0];
    acc = __builtin_amdgcn_mfma_f32_16x16x32_bf16(af, bfr, acc, 0, 0, 0);
  }
#pragma unroll
  for (int rr = 0; rr < 4; rr++)
    g.u[((size_t)b * 16 + rbase + rr) * g.dout + c0 + r16] = f2b(acc[rr]);
}

// ==================== o = u.Wv (+ cls term), 1 wave / 16-d tile ============
struct OArgs {
  const unsigned short* u; const unsigned short* WTkv; const float* kvc; const float* pcls;
  unsigned short* ob; int dout;
};
__global__ __launch_bounds__(64) void ogemm_w(OArgs ga, OArgs gb) {
  OArgs g; int bx = blockIdx.x;
  if (bx < 64) { g = ga; } else { g = gb; bx -= 64; }
  const int h = bx >> 2, dt = bx & 3;
  const int lane = threadIdx.x, r16 = lane & 15, kv8 = (lane >> 4) * 8;
  f32x4 acc[4];
#pragma unroll
  for (int mt = 0; mt < 4; mt++) { acc[mt][0]=0.f; acc[mt][1]=0.f; acc[mt][2]=0.f; acc[mt][3]=0.f; }
  const int dout = g.dout;
  const unsigned short* wp = &g.WTkv[(size_t)(1024 + h * 64 + dt * 16 + r16) * dout + kv8];
  const unsigned short* up = &g.u[((size_t)r16 * 16 + h) * dout + kv8];
#pragma unroll 2
  for (int k0 = 0; k0 < dout; k0 += 32) {
    bf16x8 bfr = *(const bf16x8*)&wp[k0];
#pragma unroll
    for (int mt = 0; mt < 4; mt++) {
      bf16x8 af = *(const bf16x8*)&up[(size_t)mt * 16 * 16 * dout + k0];
      acc[mt] = __builtin_amdgcn_mfma_f32_16x16x32_bf16(af, bfr, acc[mt], 0, 0, 0);
    }
  }
  const int rbase = (lane >> 4) * 4;
#pragma unroll
  for (int mt = 0; mt < 4; mt++)
#pragma unroll
    for (int rr = 0; rr < 4; rr++) {
      int bi = mt * 16 + rbase + rr;
      int d = h * 64 + dt * 16 + r16;
      float v = acc[mt][rr] + g.pcls[bi * 16 + h] * g.kvc[(size_t)bi * 2048 + 1024 + d];
      g.ob[(size_t)bi * INNER_ + d] = f2b(v);
    }
}

// ============================ final cls copy ===============================
__global__ __launch_bounds__(256) void final_copy(const float* clsa, float* outa, int Np1a, int dima,
                                                  const float* clsb2, float* outb, int Np1b, int dimb) {
  int x = blockIdx.x, t = threadIdx.x;
  if (x < 64) {
    for (int c = t; c < dima; c += 256)
      outa[(size_t)x * Np1a * dima + c] = clsa[(size_t)x * dima + c];
  } else {
    int b = x - 64;
    for (int c = t; c < dimb; c += 256)
      outb[(size_t)b * Np1b * dimb + c] = clsb2[(size_t)b * dimb + c];
  }
}

// ================================ host =====================================
extern "C" void kernel_launch(void* const* d_in, const int* in_sizes, int n_in,
                              void* d_out, int out_size, void* d_ws, size_t ws_size,
                              hipStream_t stream) {
  const float* sm_tokens = (const float*)d_in[0];
  const float* lg_tokens = (const float*)d_in[1];
  const float* a_pin_w  = (const float*)d_in[2];  const float* a_pin_b  = (const float*)d_in[3];
  const float* a_ng     = (const float*)d_in[4];  const float* a_nb     = (const float*)d_in[5];
  const float* a_wq     = (const float*)d_in[6];  const float* a_wkv    = (const float*)d_in[7];
  const float* a_wo     = (const float*)d_in[8];  const float* a_wob    = (const float*)d_in[9];
  const float* a_pout_w = (const float*)d_in[10]; const float* a_pout_b = (const float*)d_in[11];
  const float* b_pin_w  = (const float*)d_in[12]; const float* b_pin_b  = (const float*)d_in[13];
  const float* b_ng     = (const float*)d_in[14]; const float* b_nb     = (const float*)d_in[15];
  const float* b_wq     = (const float*)d_in[16]; const float* b_wkv    = (const float*)d_in[17];
  const float* b_wo     = (const float*)d_in[18]; const float* b_wob    = (const float*)d_in[19];
  const float* b_pout_w = (const float*)d_in[20]; const float* b_pout_b = (const float*)d_in[21];

  float* out = (float*)d_out;
  char* ws = (char*)d_ws;
  size_t off = 0;
  auto alloc = [&](size_t bytes) -> void* {
    void* pt = ws + off;
    off += (bytes + 255) & ~(size_t)255;
    return pt;
  };
  unsigned short* Abf_lg = (unsigned short*)alloc(((size_t)B_ * NLG_ + 32) * LG_ * 2);
  unsigned short* Abf_sm = (unsigned short*)alloc(((size_t)B_ * NSM_ + 32) * SM_ * 2);
  unsigned short* xT_lg  = (unsigned short*)alloc((size_t)B_ * LG_ * 224 * 2);
  unsigned short* xT_sm  = (unsigned short*)alloc((size_t)B_ * SM_ * 416 * 2);
  unsigned short* WTkv_a = (unsigned short*)alloc((size_t)4 * 2048 * LG_ * 2);
  unsigned short* WTkv_b = (unsigned short*)alloc((size_t)4 * 2048 * SM_ * 2);
  unsigned short* WTpin_a = (unsigned short*)alloc((size_t)4 * SM_ * LG_ * 2);
  unsigned short* WTpin_b = (unsigned short*)alloc((size_t)4 * LG_ * SM_ * 2);
  unsigned short* WTwq_a  = (unsigned short*)alloc((size_t)4 * LG_ * INNER_ * 2);
  unsigned short* WTwq_b  = (unsigned short*)alloc((size_t)4 * SM_ * INNER_ * 2);
  unsigned short* WTwo_a  = (unsigned short*)alloc((size_t)4 * INNER_ * LG_ * 2);
  unsigned short* WTwo_b  = (unsigned short*)alloc((size_t)4 * INNER_ * SM_ * 2);
  unsigned short* WTpout_a = (unsigned short*)alloc((size_t)4 * LG_ * SM_ * 2);
  unsigned short* WTpout_b = (unsigned short*)alloc((size_t)4 * SM_ * LG_ * 2);
  unsigned short* qt_a = (unsigned short*)alloc((size_t)B_ * 16 * LG_ * 2);
  unsigned short* qt_b = (unsigned short*)alloc((size_t)B_ * 16 * SM_ * 2);
  float* S_a = (float*)alloc((size_t)B_ * 16 * SSTR * 4);
  float* S_b = (float*)alloc((size_t)B_ * 16 * SSTR * 4);
  unsigned short* u_a  = (unsigned short*)alloc((size_t)B_ * 16 * LG_ * 2);
  unsigned short* u_b  = (unsigned short*)alloc((size_t)B_ * 16 * SM_ * 2);
  float* pcls_a = (float*)alloc((size_t)B_ * 16 * 4);
  float* pcls_b = (float*)alloc((size_t)B_ * 16 * 4);
  float* cls_sm = (float*)alloc((size_t)B_ * SM_ * 4);
  float* cls_lg = (float*)alloc((size_t)B_ * LG_ * 4);
  unsigned short* clsb_sm = (unsigned short*)alloc((size_t)B_ * SM_ * 2);
  unsigned short* clsb_lg = (unsigned short*)alloc((size_t)B_ * LG_ * 2);
  float* xbuf_a = (float*)alloc((size_t)B_ * LG_ * 4);
  float* xbuf_b = (float*)alloc((size_t)B_ * SM_ * 4);
  unsigned short* xnb_a = (unsigned short*)alloc((size_t)B_ * LG_ * 2);
  unsigned short* xnb_b = (unsigned short*)alloc((size_t)B_ * SM_ * 2);
  float* qbuf_a = (float*)alloc((size_t)B_ * INNER_ * 4);
  float* qbuf_b = (float*)alloc((size_t)B_ * INNER_ * 4);
  float* kvc_a  = (float*)alloc((size_t)B_ * 2048 * 4);
  float* kvc_b  = (float*)alloc((size_t)B_ * 2048 * 4);
  unsigned short* obufb_a = (unsigned short*)alloc((size_t)B_ * INNER_ * 2);
  unsigned short* obufb_b = (unsigned short*)alloc((size_t)B_ * INNER_ * 2);
  unsigned short* t1b_a = (unsigned short*)alloc((size_t)B_ * LG_ * 2);
  unsigned short* t1b_b = (unsigned short*)alloc((size_t)B_ * SM_ * 2);
  (void)ws_size; (void)in_sizes; (void)n_in; (void)out_size;

  const size_t sm_elems = (size_t)B_ * (NSM_ + 1) * SM_;

  // ---- setup: tokens pass
  CCArgs ca{sm_tokens, out, Abf_sm, cls_sm, clsb_sm, NSM_ + 1, SM_, B_ * (NSM_ + 1)};
  CCArgs cb{lg_tokens, out + sm_elems, Abf_lg, cls_lg, clsb_lg, NLG_ + 1, LG_, B_ * (NLG_ + 1)};
  copy_cvt<<<ca.nblk + cb.nblk, 256, 0, stream>>>(ca, cb);
  // ---- x^T (both branches, one dispatch)
  TXArgs txa{Abf_lg, xT_lg, NLG_, LG_, 224, LG_ / 64, 4, B_ * (LG_ / 64) * 4};
  TXArgs txb{Abf_sm, xT_sm, NSM_, SM_, 416, SM_ / 64, 7, B_ * (SM_ / 64) * 7};
  transpose_x2<<<txa.nblk + txb.nblk, dim3(64, 4), 0, stream>>>(txa, txb);
  // ---- all weight transposes
  WTArgs W;
  W.d[0] = {a_wkv,    WTkv_a,   LG_, 2048};
  W.d[1] = {b_wkv,    WTkv_b,   SM_, 2048};
  W.d[2] = {a_pin_w,  WTpin_a,  SM_, LG_};
  W.d[3] = {b_pin_w,  WTpin_b,  LG_, SM_};
  W.d[4] = {a_wq,     WTwq_a,   LG_, INNER_};
  W.d[5] = {b_wq,     WTwq_b,   SM_, INNER_};
  W.d[6] = {a_wo,     WTwo_a,   INNER_, LG_};
  W.d[7] = {b_wo,     WTwo_b,   INNER_, SM_};
  W.d[8] = {a_pout_w, WTpout_a, LG_, SM_};
  W.d[9] = {b_pout_w, WTpout_b, SM_, LG_};
  W.cum[0] = 0;
  for (int i = 0; i < 10; i++)
    W.cum[i + 1] = W.cum[i] + (W.d[i].K / 64) * (W.d[i].N / 64) * 4;
  wtrans_all<<<W.cum[10], 256, 0, stream>>>(W);

  for (int l = 0; l < 4; l++) {
    const unsigned short* WTpin_al = WTpin_a + (size_t)l * SM_ * LG_;
    const unsigned short* WTpin_bl = WTpin_b + (size_t)l * LG_ * SM_;
    const unsigned short* WTwq_al  = WTwq_a  + (size_t)l * LG_ * INNER_;
    const unsigned short* WTwq_bl  = WTwq_b  + (size_t)l * SM_ * INNER_;
    const unsigned short* WTkv_al  = WTkv_a  + (size_t)l * 2048 * LG_;
    const unsigned short* WTkv_bl  = WTkv_b  + (size_t)l * 2048 * SM_;
    const unsigned short* WTwo_al  = WTwo_a  + (size_t)l * INNER_ * LG_;
    const unsigned short* WTwo_bl  = WTwo_b  + (size_t)l * INNER_ * SM_;
    const unsigned short* WTpout_al = WTpout_a + (size_t)l * LG_ * SM_;
    const unsigned short* WTpout_bl = WTpout_b + (size_t)l * SM_ * LG_;

    // pin: x = cls @ pin_w + pin_b  (f32 out)
    SGArgs Gp; Gp.nd = 2;
    Gp.d[0] = {clsb_sm, WTpin_al, a_pin_b + (size_t)l * LG_, xbuf_a, nullptr, nullptr, SM_, LG_};
    Gp.d[1] = {clsb_lg, WTpin_bl, b_pin_b + (size_t)l * SM_, xbuf_b, nullptr, nullptr, LG_, SM_};
    Gp.cum[0] = 0; Gp.cum[1] = LG_ / 16; Gp.cum[2] = LG_ / 16 + SM_ / 16;
    sg_wide<<<Gp.cum[2], 64, 0, stream>>>(Gp);
    // ln
    LNArgs la{xbuf_a, xnb_a, a_ng + (size_t)l * LG_, a_nb + (size_t)l * LG_, LG_};
    LNArgs lb{xbuf_b, xnb_b, b_ng + (size_t)l * SM_, b_nb + (size_t)l * SM_, SM_};
    ln2<<<128, 256, 0, stream>>>(la, lb);
    // q (f32) + kv_cls (f32), both branches: 4 descriptors
    SGArgs Gq; Gq.nd = 4;
    Gq.d[0] = {xnb_a, WTwq_al, nullptr, qbuf_a, nullptr, nullptr, LG_, INNER_};
    Gq.d[1] = {xnb_a, WTkv_al, nullptr, kvc_a,  nullptr, nullptr, LG_, 2048};
    Gq.d[2] = {xnb_b, WTwq_bl, nullptr, qbuf_b, nullptr, nullptr, SM_, INNER_};
    Gq.d[3] = {xnb_b, WTkv_bl, nullptr, kvc_b,  nullptr, nullptr, SM_, 2048};
    Gq.cum[0] = 0; Gq.cum[1] = 64; Gq.cum[2] = 192; Gq.cum[3] = 256; Gq.cum[4] = 384;
    sg_wide<<<384, 64, 0, stream>>>(Gq);
    // q~
    qtilde2<<<dim3(24, 16), 256, 0, stream>>>(qbuf_a, a_wkv + (size_t)l * LG_ * 2048, qt_a, 16,
                                              qbuf_b, b_wkv + (size_t)l * SM_ * 2048, qt_b);
    // S = q~ . x^T
    SArgs sa{qt_a, Abf_lg, S_a, LG_, NLG_, 224 / 16, B_ * (224 / 16)};
    SArgs sb{qt_b, Abf_sm, S_b, SM_, NSM_, 416 / 16, B_ * (416 / 16)};
    s_gemm<<<sa.nblk + sb.nblk, 64, 0, stream>>>(sa, sb);
    // softmax + u = p . x
    UArgs ua{S_a, qbuf_a, kvc_a, xT_lg, u_a, pcls_a, LG_, NLG_, 224, 224, LG_ / 64, B_ * (LG_ / 64)};
    UArgs ub{S_b, qbuf_b, kvc_b, xT_sm, u_b, pcls_b, SM_, NSM_, 416, 416, SM_ / 64, B_ * (SM_ / 64)};
    usoftmax<<<ua.nblk + ub.nblk, 256, 0, stream>>>(ua, ub);
    // o = u . Wv + pcls * v_cls
    OArgs oa{u_a, WTkv_al, kvc_a, pcls_a, obufb_a, LG_};
    OArgs ob{u_b, WTkv_bl, kvc_b, pcls_b, obufb_b, SM_};
    ogemm_w<<<128, 64, 0, stream>>>(oa, ob);
    // wo
    SGArgs Gw; Gw.nd = 2;
    Gw.d[0] = {obufb_a, WTwo_al, a_wob + (size_t)l * LG_, nullptr, t1b_a, nullptr, INNER_, LG_};
    Gw.d[1] = {obufb_b, WTwo_bl, b_wob + (size_t)l * SM_, nullptr, t1b_b, nullptr, INNER_, SM_};
    Gw.cum[0] = 0; Gw.cum[1] = LG_ / 16; Gw.cum[2] = LG_ / 16 + SM_ / 16;
    sg_wide<<<Gw.cum[2], 64, 0, stream>>>(Gw);
    // pout + residual (f32 += , bf16 mirror)
    SGArgs Gr; Gr.nd = 2;
    Gr.d[0] = {t1b_a, WTpout_al, a_pout_b + (size_t)l * SM_, cls_sm, clsb_sm, cls_sm, LG_, SM_};
    Gr.d[1] = {t1b_b, WTpout_bl, b_pout_b + (size_t)l * LG_, cls_lg, clsb_lg, cls_lg, SM_, LG_};
    Gr.cum[0] = 0; Gr.cum[1] = SM_ / 16; Gr.cum[2] = SM_ / 16 + LG_ / 16;
    sg_wide<<<Gr.cum[2], 64, 0, stream>>>(Gr);
  }

  final_copy<<<128, 256, 0, stream>>>(cls_sm, out, NSM_ + 1, SM_,
                                      cls_lg, out + sm_elems, NLG_ + 1, LG_);
}